// Round 11
// baseline (517.853 us; speedup 1.0000x reference)
//
#include <hip/hip_runtime.h>
#include <hip/hip_bf16.h>

#define BD 2
#define HD 480
#define WD 480
#define CD 32
#define HALFD 16
#define WND 20
#define NP 500
#define PLANE (HD*WD)
#define TWO_PI_OVER_NP 0.012566370614359172954f  /* 2*pi/500 */

typedef __attribute__((ext_vector_type(8))) short bf16x8;
typedef __attribute__((ext_vector_type(4))) float f32x4;

__device__ __forceinline__ float gelu_f(float x) {
    return 0.5f * x * (1.0f + erff(x * 0.70710678118654752f));
}
__device__ __forceinline__ float bfbits2f(short s) {
    unsigned u = ((unsigned)(unsigned short)s) << 16;
    return __uint_as_float(u);
}
__device__ __forceinline__ short bf16s(float v) {
    __hip_bfloat16 b = __float2bfloat16(v);
    return *reinterpret_cast<short*>(&b);
}

// Input MLPs: a -> A (planar) + A2 (pixel-major); e -> E (planar, layer-invariant).
__global__ void __launch_bounds__(256) k_ae(
    const float* src, const float* inp,
    const float* iw1, const float* ib1,
    const float* iw2, const float* ib2,
    const float* ew1, const float* eb1,
    const float* ew2, const float* eb2,
    __hip_bfloat16* A, __hip_bfloat16* A2, __hip_bfloat16* E)
{
    __shared__ float s_iw1[80], s_ib1[16], s_iw2[512], s_ib2[32];
    __shared__ float s_ew1[48], s_eb1[16], s_ew2[512], s_eb2[32];
    int tid = threadIdx.x;
    for (int t = tid; t < 512; t += 256) s_iw2[t] = iw2[t];
    for (int t = tid; t < 512; t += 256) s_ew2[t] = ew2[t];
    if (tid < 80) s_iw1[tid] = iw1[tid];
    if (tid >= 96 && tid < 112) s_ib1[tid - 96] = ib1[tid - 96];
    if (tid >= 128 && tid < 160) s_ib2[tid - 128] = ib2[tid - 128];
    if (tid >= 160 && tid < 208) s_ew1[tid - 160] = ew1[tid - 160];
    if (tid >= 208 && tid < 224) s_eb1[tid - 208] = eb1[tid - 208];
    if (tid >= 224 && tid < 256) s_eb2[tid - 224] = eb2[tid - 224];
    __syncthreads();
    int gid = blockIdx.x * 256 + tid;  // < 460800
    int b = gid / PLANE;
    int r = gid % PLANE;
    int h = r / WD, w = r % WD;
    float gx = (float)h * (1.0f / 479.0f);
    float gy = (float)w * (1.0f / 479.0f);
    float s0 = src[(size_t)gid * 3 + 0];
    float s1 = src[(size_t)gid * 3 + 1];
    float s2 = src[(size_t)gid * 3 + 2];
    float hid[16];
    #pragma unroll
    for (int j = 0; j < 16; j++) {
        float v = s_ib1[j] + s0 * s_iw1[j] + s1 * s_iw1[16 + j] + s2 * s_iw1[32 + j]
                + gx * s_iw1[48 + j] + gy * s_iw1[64 + j];
        hid[j] = gelu_f(v);
    }
    __hip_bfloat16* Ap = A + (size_t)b * CD * PLANE + r;
    unsigned pk[16];
    for (int c = 0; c < 32; c++) {
        float v = s_ib2[c];
        #pragma unroll
        for (int j = 0; j < 16; j++) v += hid[j] * s_iw2[j * 32 + c];
        Ap[(size_t)c * PLANE] = __float2bfloat16(v);
        unsigned short us = (unsigned short)bf16s(v);
        if (c & 1) pk[c >> 1] |= ((unsigned)us) << 16; else pk[c >> 1] = us;
    }
    uint4* A2p = reinterpret_cast<uint4*>(A2 + (size_t)gid * 32);
    #pragma unroll
    for (int q = 0; q < 4; q++)
        A2p[q] = make_uint4(pk[q * 4], pk[q * 4 + 1], pk[q * 4 + 2], pk[q * 4 + 3]);
    float xi = inp[gid];
    #pragma unroll
    for (int j = 0; j < 16; j++) {
        float v = s_eb1[j] + xi * s_ew1[j] + gx * s_ew1[16 + j] + gy * s_ew1[32 + j];
        hid[j] = gelu_f(v);
    }
    __hip_bfloat16* Ep = E + (size_t)b * CD * PLANE + r;
    for (int c = 0; c < 32; c++) {
        float e = s_eb2[c];
        #pragma unroll
        for (int j = 0; j < 16; j++) e += hid[j] * s_ew2[j * 32 + c];
        Ep[(size_t)c * PLANE] = __float2bfloat16(e);
    }
}

// All four swizzled twiddle fragment tables:
// Twig[0,45) | TinvF[45,105) | Tf2[105,255) | Ti1[255,435).
// TinvF has the irfft scale (ky==0?1:2)/250000 baked in (zero rows kk>=40
// also absorb U2's unwritten pad region -> garbage*0 = 0).
__global__ void k_tables(__hip_bfloat16* T) {
    int e = blockIdx.x * 256 + threadIdx.x;   // < 435*512
    if (e >= 435 * 512) return;
    int tile = e >> 9, r = e & 511;
    int lane = r >> 3, j = r & 7;
    float v = 0.0f;
    if (tile < 45) {                       // Twig: F1 row-DFT (K=480, N=48 pad)
        int kt = tile / 3, nt = tile % 3;
        int k = kt * 32 + ((lane >> 4) << 3) + j;
        int n = nt * 16 + (lane & 15);
        if (n < 40) {
            int ky = n >> 1;
            int idx = (k * ky) % NP;
            float ang = (float)idx * TWO_PI_OVER_NP;
            v = (n & 1) ? -sinf(ang) : cosf(ang);
        }
    } else if (tile < 105) {               // TinvF: I2 inverse-ky (K=64 pad, N=480)
        int t2 = tile - 45;
        int nt = t2 >> 1, kt = t2 & 1;
        int kk = kt * 32 + ((lane >> 4) << 3) + j;
        int w = nt * 16 + (lane & 15);
        if (kk < 40) {
            int ky = kk >> 1;
            int idx = (ky * w) % NP;
            float ang = (float)idx * TWO_PI_OVER_NP;
            float sc = (ky == 0 ? 1.0f : 2.0f) * (1.0f / 250000.0f);
            v = ((kk & 1) ? -sinf(ang) : cosf(ang)) * sc;
        }
    } else if (tile < 255) {               // Tf2: F2 h-DFT (K=960, N=80)
        int t2 = tile - 105;
        int kt = t2 / 5, nt = t2 % 5;
        int k = kt * 32 + ((lane >> 4) << 3) + j;
        int n = nt * 16 + (lane & 15);
        int hh = k >> 1, ri = k & 1;
        int kxi = n >> 1, part = n & 1;
        int kx = (kxi < 20) ? kxi : kxi + 460;
        int idx = (kx * hh) % NP;
        float ang = (float)idx * TWO_PI_OVER_NP;
        float c = cosf(ang), s = sinf(ang);
        v = (part == 0) ? (ri == 0 ? c : s) : (ri == 0 ? -s : c);
    } else {                               // Ti1: I1 inverse-kx (K=96 pad, N=960)
        int t2 = tile - 255;
        int nt = t2 / 3, kt = t2 % 3;
        int k = kt * 32 + ((lane >> 4) << 3) + j;
        int n = nt * 16 + (lane & 15);
        if (k < 80) {
            int kxi = k >> 1, ri = k & 1;
            int hh = n >> 1, part = n & 1;
            int kx = (kxi < 20) ? kxi : kxi + 460;
            int idx = (kx * hh) % NP;
            float ang = (float)idx * TWO_PI_OVER_NP;
            float c = cosf(ang), s = sinf(ang);
            v = (part == 0) ? (ri == 0 ? c : -s) : (ri == 0 ? s : c);
        }
    }
    T[e] = __float2bfloat16(v);
}

// F1 as pure global-operand MFMA GEMM; A-fragment formed on the fly as A ⊙ E.
__global__ void __launch_bounds__(256) k_F1m(
    const __hip_bfloat16* A, const __hip_bfloat16* E,
    const __hip_bfloat16* Twig, __hip_bfloat16* Y1)
{
    int wv = threadIdx.x >> 6, lane = threadIdx.x & 63;
    int task = blockIdx.x * 4 + wv;          // < 5760
    int bh = task / 6, rem = task % 6;
    int mt = rem & 1, nt = rem >> 1;
    int b = bh / HD, h = bh % HD;
    int c = mt * 16 + (lane & 15);
    int koff = (lane >> 4) << 3;
    size_t base = ((size_t)(b * 32 + c)) * PLANE + (size_t)h * WD + koff;
    const __hip_bfloat16* arow = A + base;
    const __hip_bfloat16* erow = E + base;
    f32x4 acc = {0.f, 0.f, 0.f, 0.f};
    #pragma unroll
    for (int kt = 0; kt < 15; kt++) {
        bf16x8 av = *reinterpret_cast<const bf16x8*>(arow + kt * 32);
        bf16x8 ev = *reinterpret_cast<const bf16x8*>(erow + kt * 32);
        bf16x8 gv;
        #pragma unroll
        for (int j = 0; j < 8; j++)
            gv[j] = bf16s(bfbits2f(av[j]) * bfbits2f(ev[j]));
        bf16x8 bv = *reinterpret_cast<const bf16x8*>(Twig + (((kt * 3 + nt) << 9) + lane * 8));
        acc = __builtin_amdgcn_mfma_f32_16x16x32_bf16(gv, bv, acc, 0, 0, 0);
    }
    int n = nt * 16 + (lane & 15);
    if (n < 40) {
        int ky = n >> 1, part = n & 1;
        int crow = mt * 16 + ((lane >> 4) << 2);
        #pragma unroll
        for (int r = 0; r < 4; r++) {
            int cc = crow + r;
            Y1[((((size_t)(b * 32 + cc)) * WND + ky) * HD + h) * 2 + part] =
                __float2bfloat16(acc[r]);
        }
    }
}

// F2 as MFMA GEMM: M=1280 rows, K=960, N=80.
__global__ void __launch_bounds__(256) k_F2m(
    const __hip_bfloat16* Y1, const __hip_bfloat16* Tf2, float* Y2)
{
    int wv = threadIdx.x >> 6, lane = threadIdx.x & 63;
    int task = blockIdx.x * 4 + wv;          // < 400
    int mt = task / 5, nt = task % 5;
    int row = mt * 16 + (lane & 15);
    int koff = (lane >> 4) << 3;
    const __hip_bfloat16* arow = Y1 + (size_t)row * 960 + koff;
    f32x4 acc = {0.f, 0.f, 0.f, 0.f};
    #pragma unroll
    for (int kt = 0; kt < 30; kt++) {
        bf16x8 av = *reinterpret_cast<const bf16x8*>(arow + kt * 32);
        bf16x8 bv = *reinterpret_cast<const bf16x8*>(Tf2 + (((kt * 5 + nt) << 9) + lane * 8));
        acc = __builtin_amdgcn_mfma_f32_16x16x32_bf16(av, bv, acc, 0, 0, 0);
    }
    int n = nt * 16 + (lane & 15);
    int mb = mt * 16 + ((lane >> 4) << 2);
    #pragma unroll
    for (int r = 0; r < 4; r++)
        Y2[(size_t)(mb + r) * 80 + n] = acc[r];
}

// Channel mixing; writes Zb as bf16 rows [m][96] (cols 80..95 zero).
__global__ void __launch_bounds__(256) k_mix(
    const float* Y2, __hip_bfloat16* Zb,
    const float* fw1, const float* fw2, int l)
{
    int gid = blockIdx.x * 256 + threadIdx.x;  // < 122880
    int col = gid % 96;
    int row = gid / 96;
    if (col >= 80) { Zb[gid] = __float2bfloat16(0.0f); return; }
    int ky = row % 20;
    int oc = (row / 20) % 32;
    int b = row / 640;
    int z = col & 1;
    int kxi = col >> 1;
    const float* wp;
    int x;
    if (kxi < 20) { wp = fw1; x = kxi; } else { wp = fw2; x = kxi - 20; }
    size_t wbase = ((((size_t)(l * 32) * 32 + oc) * 20 + x) * 20 + ky) * 2 + z;
    const float* y2 = Y2 + ((size_t)b * 32 * 20 + ky) * 80 + kxi * 2 + z;
    float acc = 0.f;
    for (int i = 0; i < 32; i++) {
        float yv = y2[(size_t)i * 1600];
        float wv = wp[wbase + (size_t)i * 25600];
        acc += yv * wv;
    }
    Zb[gid] = __float2bfloat16(acc);
}

// I1 as MFMA GEMM: M=1280 rows (b,oc,ky), K=96 pad, N=960 (h,re/im).
// Writes U2 in per-(b,h) fragment blocks: U2[((b*480+h)*32 + oc)*64 + ky*2+part].
// kk in [40,64) is never written; TinvF zero-rows nullify it in the I2 GEMM.
__global__ void __launch_bounds__(256) k_I1m(
    const __hip_bfloat16* Zb, const __hip_bfloat16* Ti1, __hip_bfloat16* U2)
{
    int wv = threadIdx.x >> 6, lane = threadIdx.x & 63;
    int task = blockIdx.x * 4 + wv;          // < 4800
    int mt = task / 60, nt = task % 60;
    int row = mt * 16 + (lane & 15);
    int koff = (lane >> 4) << 3;
    const __hip_bfloat16* arow = Zb + (size_t)row * 96 + koff;
    f32x4 acc = {0.f, 0.f, 0.f, 0.f};
    #pragma unroll
    for (int kt = 0; kt < 3; kt++) {
        bf16x8 av = *reinterpret_cast<const bf16x8*>(arow + kt * 32);
        bf16x8 bv = *reinterpret_cast<const bf16x8*>(Ti1 + (((nt * 3 + kt) << 9) + lane * 8));
        acc = __builtin_amdgcn_mfma_f32_16x16x32_bf16(av, bv, acc, 0, 0, 0);
    }
    int n = nt * 16 + (lane & 15);
    int hh = n >> 1, part = n & 1;
    int mb = mt * 16 + ((lane >> 4) << 2);
    #pragma unroll
    for (int r = 0; r < 4; r++) {
        int rr = mb + r;
        int ky = rr % 20, oc = (rr / 20) % 32, b = rr / 640;
        U2[(((size_t)b * HD + hh) * 32 + oc) * 64 + ky * 2 + part] =
            __float2bfloat16(acc[r]);
    }
}

// I2 as pure LDS-free GEMM per (b,h): Anew[oc][w] = act(U-DFT + conv + bias).
// U A-frags: aligned 16B loads from U2 block. Conv B-frags: aligned 16B loads
// from pixel-major A2in. Outputs: planar A (for F1m, l<3) + pixel-major A2out.
// No LDS, no barriers, no in-place hazard (A2 ping-pong).
__global__ void __launch_bounds__(256) k_I2m(
    const __hip_bfloat16* U2, const __hip_bfloat16* A2in,
    __hip_bfloat16* A, __hip_bfloat16* A2out,
    const float* convw, const float* convb,
    const __hip_bfloat16* TinvF,
    int l, int do_gelu, int write_planar)
{
    int tid = threadIdx.x;
    int wv = tid >> 6, lane = tid & 63;
    int bh = blockIdx.x;                 // b*480 + h
    int b = bh / HD, h = bh % HD;
    int mrow = lane & 15, koff = (lane >> 4) << 3;
    int ocq = (lane >> 4) << 2;
    bf16x8 uf[2][2], wf[2];
    float bias[2][4];
    const __hip_bfloat16* U2b = U2 + (size_t)bh * 32 * 64;
    #pragma unroll
    for (int mt = 0; mt < 2; mt++) {
        int oc = mt * 16 + mrow;
        #pragma unroll
        for (int kt = 0; kt < 2; kt++)
            uf[mt][kt] = *reinterpret_cast<const bf16x8*>(U2b + oc * 64 + kt * 32 + koff);
        bf16x8 wvv;
        #pragma unroll
        for (int j = 0; j < 8; j++)
            wvv[j] = bf16s(convw[(size_t)l * 1024 + oc * 32 + koff + j]);
        wf[mt] = wvv;
        #pragma unroll
        for (int r = 0; r < 4; r++)
            bias[mt][r] = convb[l * 32 + mt * 16 + ocq + r];
    }
    const __hip_bfloat16* A2r = A2in + (size_t)bh * WD * 32;
    for (int i = 0; i < 15; i++) {
        int t = wv + 4 * i;
        int mt = t & 1, nt = t >> 1;
        f32x4 acc = {0.f, 0.f, 0.f, 0.f};
        #pragma unroll
        for (int kt = 0; kt < 2; kt++) {
            bf16x8 bv = *reinterpret_cast<const bf16x8*>(TinvF + (((nt * 2 + kt) << 9) + lane * 8));
            acc = __builtin_amdgcn_mfma_f32_16x16x32_bf16(uf[mt][kt], bv, acc, 0, 0, 0);
        }
        bf16x8 bv2 = *reinterpret_cast<const bf16x8*>(A2r + ((nt * 16 + mrow) << 5) + koff);
        acc = __builtin_amdgcn_mfma_f32_16x16x32_bf16(wf[mt], bv2, acc, 0, 0, 0);
        int w = nt * 16 + mrow;
        int ocb = mt * 16 + ocq;
        unsigned short us[4];
        #pragma unroll
        for (int r = 0; r < 4; r++) {
            float v = acc[r] + bias[mt][r];
            if (do_gelu) v = gelu_f(v);
            us[r] = (unsigned short)bf16s(v);
            if (write_planar)
                A[((size_t)b * CD + (ocb + r)) * PLANE + (size_t)h * WD + w] =
                    __float2bfloat16(v);
        }
        uint2 pk;
        pk.x = (unsigned)us[0] | ((unsigned)us[1] << 16);
        pk.y = (unsigned)us[2] | ((unsigned)us[3] << 16);
        *reinterpret_cast<uint2*>(A2out + (((size_t)bh * WD + w) << 5) + ocb) = pk;
    }
}

// Final: proj MLP + 3x3 mask conv + field*mask + pred. Reads pixel-major A2.
__global__ void __launch_bounds__(256) k_out(
    const __hip_bfloat16* A2fin, const float* inp, const float* src,
    const float* pw1, const float* pb1,
    const float* pw2, const float* pb2,
    const float* mw, const float* mb,
    float* out)
{
    __shared__ float sW1[CD * HALFD], sB1[HALFD], sW2[HALFD * 2], sB2[2], sM[9], sMB[1];
    int tid = threadIdx.x;
    for (int t = tid; t < CD * HALFD; t += 256) sW1[t] = pw1[t];
    if (tid < 16) sB1[tid] = pb1[tid];
    if (tid >= 32 && tid < 64) sW2[tid - 32] = pw2[tid - 32];
    if (tid >= 64 && tid < 66) sB2[tid - 64] = pb2[tid - 64];
    if (tid >= 96 && tid < 105) sM[tid - 96] = mw[tid - 96];
    if (tid == 128) sMB[0] = mb[0];
    __syncthreads();
    int gid = blockIdx.x * 256 + tid;  // < 460800
    int b = gid / PLANE;
    int r = gid % PLANE;
    int h = r / WD, w = r % WD;
    const bf16x8* ap = reinterpret_cast<const bf16x8*>(A2fin + (size_t)gid * 32);
    float av[32];
    #pragma unroll
    for (int q = 0; q < 4; q++) {
        bf16x8 v = ap[q];
        #pragma unroll
        for (int j = 0; j < 8; j++) av[q * 8 + j] = bfbits2f(v[j]);
    }
    float hid[16];
    #pragma unroll
    for (int j = 0; j < 16; j++) {
        float v = sB1[j];
        #pragma unroll
        for (int i = 0; i < 32; i++) v += av[i] * sW1[i * 16 + j];
        hid[j] = gelu_f(v);
    }
    float p0 = sB2[0], p1 = sB2[1];
    #pragma unroll
    for (int j = 0; j < 16; j++) { p0 += hid[j] * sW2[j * 2]; p1 += hid[j] * sW2[j * 2 + 1]; }
    float m = sMB[0];
    #pragma unroll
    for (int dh = 0; dh < 3; dh++) {
        int hh = h + dh - 1;
        #pragma unroll
        for (int dw = 0; dw < 3; dw++) {
            int ww = w + dw - 1;
            if (hh >= 0 && hh < HD && ww >= 0 && ww < WD)
                m += inp[(size_t)b * PLANE + (size_t)hh * WD + ww] * sM[dh * 3 + dw];
        }
    }
    float f0 = src[(size_t)gid * 3 + 1];
    float f1 = src[(size_t)gid * 3 + 2];
    out[(size_t)gid * 2 + 0] = f0 * m + p0;
    out[(size_t)gid * 2 + 1] = f1 * m + p1;
}

extern "C" void kernel_launch(void* const* d_in, const int* in_sizes, int n_in,
                              void* d_out, int out_size, void* d_ws, size_t ws_size,
                              hipStream_t stream) {
    const float* inp = (const float*)d_in[0];
    const float* src = (const float*)d_in[1];
    const float* iw1 = (const float*)d_in[2];
    const float* ib1 = (const float*)d_in[3];
    const float* iw2 = (const float*)d_in[4];
    const float* ib2 = (const float*)d_in[5];
    const float* ew1 = (const float*)d_in[6];
    const float* eb1 = (const float*)d_in[7];
    const float* ew2 = (const float*)d_in[8];
    const float* eb2 = (const float*)d_in[9];
    const float* fw1 = (const float*)d_in[10];
    const float* fw2 = (const float*)d_in[11];
    const float* cw  = (const float*)d_in[12];
    const float* cb  = (const float*)d_in[13];
    const float* pw1 = (const float*)d_in[14];
    const float* pb1 = (const float*)d_in[15];
    const float* pw2 = (const float*)d_in[16];
    const float* pb2 = (const float*)d_in[17];
    const float* mw  = (const float*)d_in[18];
    const float* mb  = (const float*)d_in[19];

    // Workspace (~125.5 MB; ws is 256 MiB per fillBuffer evidence):
    //   A planar bf16 | E planar bf16 | A2a, A2b pixel-major bf16 (ping-pong)
    //   | Y1 bf16 | Y2 f32 | Zb bf16 | U2 bf16 [bh][32][64] | tables bf16
    const size_t NA = (size_t)BD * CD * PLANE;
    __hip_bfloat16* A   = (__hip_bfloat16*)d_ws;
    __hip_bfloat16* E   = A + NA;
    __hip_bfloat16* A2a = E + NA;
    __hip_bfloat16* A2b = A2a + NA;
    __hip_bfloat16* Y1  = A2b + NA;
    float* Y2 = (float*)(Y1 + (size_t)BD * CD * WND * HD * 2);
    __hip_bfloat16* Zb = (__hip_bfloat16*)(Y2 + 1280 * 80);
    __hip_bfloat16* U2 = Zb + 1280 * 96;
    __hip_bfloat16* Tbl   = U2 + (size_t)BD * HD * 32 * 64;
    __hip_bfloat16* Twig  = Tbl;
    __hip_bfloat16* TinvF = Twig + 45 * 512;
    __hip_bfloat16* Tf2   = TinvF + 60 * 512;
    __hip_bfloat16* Ti1   = Tf2 + 150 * 512;

    k_tables<<<870, 256, 0, stream>>>(Tbl);
    k_ae<<<1800, 256, 0, stream>>>(src, inp, iw1, ib1, iw2, ib2,
                                   ew1, eb1, ew2, eb2, A, A2a, E);

    __hip_bfloat16* ping[2] = {A2a, A2b};
    for (int l = 0; l < 4; l++) {
        k_F1m<<<1440, 256, 0, stream>>>(A, E, Twig, Y1);
        k_F2m<<<100, 256, 0, stream>>>(Y1, Tf2, Y2);
        k_mix<<<480, 256, 0, stream>>>(Y2, Zb, fw1, fw2, l);
        k_I1m<<<1200, 256, 0, stream>>>(Zb, Ti1, U2);
        k_I2m<<<BD * HD, 256, 0, stream>>>(U2, ping[l & 1], A, ping[(l + 1) & 1],
                                           cw, cb, TinvF,
                                           l, (l < 3) ? 1 : 0, (l < 3) ? 1 : 0);
    }
    k_out<<<1800, 256, 0, stream>>>(ping[0], inp, src, pw1, pb1, pw2, pb2, mw, mb,
                                    (float*)d_out);
}

// Round 12
// 509.085 us; speedup vs baseline: 1.0172x; 1.0172x over previous
//
#include <hip/hip_runtime.h>
#include <hip/hip_bf16.h>

#define BD 2
#define HD 480
#define WD 480
#define CD 32
#define HALFD 16
#define WND 20
#define NP 500
#define PLANE (HD*WD)
#define TWO_PI_OVER_NP 0.012566370614359172954f  /* 2*pi/500 */

typedef __attribute__((ext_vector_type(8))) short bf16x8;
typedef __attribute__((ext_vector_type(4))) float f32x4;

__device__ __forceinline__ float gelu_f(float x) {
    return 0.5f * x * (1.0f + erff(x * 0.70710678118654752f));
}
__device__ __forceinline__ float bfbits2f(short s) {
    unsigned u = ((unsigned)(unsigned short)s) << 16;
    return __uint_as_float(u);
}
__device__ __forceinline__ short bf16s(float v) {
    __hip_bfloat16 b = __float2bfloat16(v);
    return *reinterpret_cast<short*>(&b);
}

// Input MLPs: a -> A (planar) + A2 (pixel-major); e -> E (planar, layer-invariant).
__global__ void __launch_bounds__(256) k_ae(
    const float* src, const float* inp,
    const float* iw1, const float* ib1,
    const float* iw2, const float* ib2,
    const float* ew1, const float* eb1,
    const float* ew2, const float* eb2,
    __hip_bfloat16* A, __hip_bfloat16* A2, __hip_bfloat16* E)
{
    __shared__ float s_iw1[80], s_ib1[16], s_iw2[512], s_ib2[32];
    __shared__ float s_ew1[48], s_eb1[16], s_ew2[512], s_eb2[32];
    int tid = threadIdx.x;
    for (int t = tid; t < 512; t += 256) s_iw2[t] = iw2[t];
    for (int t = tid; t < 512; t += 256) s_ew2[t] = ew2[t];
    if (tid < 80) s_iw1[tid] = iw1[tid];
    if (tid >= 96 && tid < 112) s_ib1[tid - 96] = ib1[tid - 96];
    if (tid >= 128 && tid < 160) s_ib2[tid - 128] = ib2[tid - 128];
    if (tid >= 160 && tid < 208) s_ew1[tid - 160] = ew1[tid - 160];
    if (tid >= 208 && tid < 224) s_eb1[tid - 208] = eb1[tid - 208];
    if (tid >= 224 && tid < 256) s_eb2[tid - 224] = eb2[tid - 224];
    __syncthreads();
    int gid = blockIdx.x * 256 + tid;  // < 460800
    int b = gid / PLANE;
    int r = gid % PLANE;
    int h = r / WD, w = r % WD;
    float gx = (float)h * (1.0f / 479.0f);
    float gy = (float)w * (1.0f / 479.0f);
    float s0 = src[(size_t)gid * 3 + 0];
    float s1 = src[(size_t)gid * 3 + 1];
    float s2 = src[(size_t)gid * 3 + 2];
    float hid[16];
    #pragma unroll
    for (int j = 0; j < 16; j++) {
        float v = s_ib1[j] + s0 * s_iw1[j] + s1 * s_iw1[16 + j] + s2 * s_iw1[32 + j]
                + gx * s_iw1[48 + j] + gy * s_iw1[64 + j];
        hid[j] = gelu_f(v);
    }
    __hip_bfloat16* Ap = A + (size_t)b * CD * PLANE + r;
    unsigned pk[16];
    for (int c = 0; c < 32; c++) {
        float v = s_ib2[c];
        #pragma unroll
        for (int j = 0; j < 16; j++) v += hid[j] * s_iw2[j * 32 + c];
        Ap[(size_t)c * PLANE] = __float2bfloat16(v);
        unsigned short us = (unsigned short)bf16s(v);
        if (c & 1) pk[c >> 1] |= ((unsigned)us) << 16; else pk[c >> 1] = us;
    }
    uint4* A2p = reinterpret_cast<uint4*>(A2 + (size_t)gid * 32);
    #pragma unroll
    for (int q = 0; q < 4; q++)
        A2p[q] = make_uint4(pk[q * 4], pk[q * 4 + 1], pk[q * 4 + 2], pk[q * 4 + 3]);
    float xi = inp[gid];
    #pragma unroll
    for (int j = 0; j < 16; j++) {
        float v = s_eb1[j] + xi * s_ew1[j] + gx * s_ew1[16 + j] + gy * s_ew1[32 + j];
        hid[j] = gelu_f(v);
    }
    __hip_bfloat16* Ep = E + (size_t)b * CD * PLANE + r;
    for (int c = 0; c < 32; c++) {
        float e = s_eb2[c];
        #pragma unroll
        for (int j = 0; j < 16; j++) e += hid[j] * s_ew2[j * 32 + c];
        Ep[(size_t)c * PLANE] = __float2bfloat16(e);
    }
}

// All four swizzled twiddle fragment tables:
// Twig[0,45) | TinvF[45,105) | Tf2[105,255) | Ti1[255,435).
// TinvF has the irfft scale baked in (zero rows kk>=40 absorb U2's pad).
// Ti1 serves as the *A-operand* of the transposed I1 GEMM unchanged — A and B
// fragment layouts are mirrored, so the same table works for either role.
__global__ void k_tables(__hip_bfloat16* T) {
    int e = blockIdx.x * 256 + threadIdx.x;   // < 435*512
    if (e >= 435 * 512) return;
    int tile = e >> 9, r = e & 511;
    int lane = r >> 3, j = r & 7;
    float v = 0.0f;
    if (tile < 45) {                       // Twig: F1 row-DFT (K=480, N=48 pad)
        int kt = tile / 3, nt = tile % 3;
        int k = kt * 32 + ((lane >> 4) << 3) + j;
        int n = nt * 16 + (lane & 15);
        if (n < 40) {
            int ky = n >> 1;
            int idx = (k * ky) % NP;
            float ang = (float)idx * TWO_PI_OVER_NP;
            v = (n & 1) ? -sinf(ang) : cosf(ang);
        }
    } else if (tile < 105) {               // TinvF: I2 inverse-ky (K=64 pad, N=480)
        int t2 = tile - 45;
        int nt = t2 >> 1, kt = t2 & 1;
        int kk = kt * 32 + ((lane >> 4) << 3) + j;
        int w = nt * 16 + (lane & 15);
        if (kk < 40) {
            int ky = kk >> 1;
            int idx = (ky * w) % NP;
            float ang = (float)idx * TWO_PI_OVER_NP;
            float sc = (ky == 0 ? 1.0f : 2.0f) * (1.0f / 250000.0f);
            v = ((kk & 1) ? -sinf(ang) : cosf(ang)) * sc;
        }
    } else if (tile < 255) {               // Tf2: F2 h-DFT (K=960, N=80)
        int t2 = tile - 105;
        int kt = t2 / 5, nt = t2 % 5;
        int k = kt * 32 + ((lane >> 4) << 3) + j;
        int n = nt * 16 + (lane & 15);
        int hh = k >> 1, ri = k & 1;
        int kxi = n >> 1, part = n & 1;
        int kx = (kxi < 20) ? kxi : kxi + 460;
        int idx = (kx * hh) % NP;
        float ang = (float)idx * TWO_PI_OVER_NP;
        float c = cosf(ang), s = sinf(ang);
        v = (part == 0) ? (ri == 0 ? c : s) : (ri == 0 ? -s : c);
    } else {                               // Ti1: (hh,part)-major twiddles, K=(kxi,ri) pad 96
        int t2 = tile - 255;
        int nt = t2 / 3, kt = t2 % 3;
        int k = kt * 32 + ((lane >> 4) << 3) + j;
        int n = nt * 16 + (lane & 15);
        if (k < 80) {
            int kxi = k >> 1, ri = k & 1;
            int hh = n >> 1, part = n & 1;
            int kx = (kxi < 20) ? kxi : kxi + 460;
            int idx = (kx * hh) % NP;
            float ang = (float)idx * TWO_PI_OVER_NP;
            float c = cosf(ang), s = sinf(ang);
            v = (part == 0) ? (ri == 0 ? c : -s) : (ri == 0 ? s : c);
        }
    }
    T[e] = __float2bfloat16(v);
}

// F1 as pure global-operand MFMA GEMM; A-fragment formed on the fly as A ⊙ E.
__global__ void __launch_bounds__(256) k_F1m(
    const __hip_bfloat16* A, const __hip_bfloat16* E,
    const __hip_bfloat16* Twig, __hip_bfloat16* Y1)
{
    int wv = threadIdx.x >> 6, lane = threadIdx.x & 63;
    int task = blockIdx.x * 4 + wv;          // < 5760
    int bh = task / 6, rem = task % 6;
    int mt = rem & 1, nt = rem >> 1;
    int b = bh / HD, h = bh % HD;
    int c = mt * 16 + (lane & 15);
    int koff = (lane >> 4) << 3;
    size_t base = ((size_t)(b * 32 + c)) * PLANE + (size_t)h * WD + koff;
    const __hip_bfloat16* arow = A + base;
    const __hip_bfloat16* erow = E + base;
    f32x4 acc = {0.f, 0.f, 0.f, 0.f};
    #pragma unroll
    for (int kt = 0; kt < 15; kt++) {
        bf16x8 av = *reinterpret_cast<const bf16x8*>(arow + kt * 32);
        bf16x8 ev = *reinterpret_cast<const bf16x8*>(erow + kt * 32);
        bf16x8 gv;
        #pragma unroll
        for (int j = 0; j < 8; j++)
            gv[j] = bf16s(bfbits2f(av[j]) * bfbits2f(ev[j]));
        bf16x8 bv = *reinterpret_cast<const bf16x8*>(Twig + (((kt * 3 + nt) << 9) + lane * 8));
        acc = __builtin_amdgcn_mfma_f32_16x16x32_bf16(gv, bv, acc, 0, 0, 0);
    }
    int n = nt * 16 + (lane & 15);
    if (n < 40) {
        int ky = n >> 1, part = n & 1;
        int crow = mt * 16 + ((lane >> 4) << 2);
        #pragma unroll
        for (int r = 0; r < 4; r++) {
            int cc = crow + r;
            Y1[((((size_t)(b * 32 + cc)) * WND + ky) * HD + h) * 2 + part] =
                __float2bfloat16(acc[r]);
        }
    }
}

// F2 as MFMA GEMM: M=1280 rows, K=960, N=80.
__global__ void __launch_bounds__(256) k_F2m(
    const __hip_bfloat16* Y1, const __hip_bfloat16* Tf2, float* Y2)
{
    int wv = threadIdx.x >> 6, lane = threadIdx.x & 63;
    int task = blockIdx.x * 4 + wv;          // < 400
    int mt = task / 5, nt = task % 5;
    int row = mt * 16 + (lane & 15);
    int koff = (lane >> 4) << 3;
    const __hip_bfloat16* arow = Y1 + (size_t)row * 960 + koff;
    f32x4 acc = {0.f, 0.f, 0.f, 0.f};
    #pragma unroll
    for (int kt = 0; kt < 30; kt++) {
        bf16x8 av = *reinterpret_cast<const bf16x8*>(arow + kt * 32);
        bf16x8 bv = *reinterpret_cast<const bf16x8*>(Tf2 + (((kt * 5 + nt) << 9) + lane * 8));
        acc = __builtin_amdgcn_mfma_f32_16x16x32_bf16(av, bv, acc, 0, 0, 0);
    }
    int n = nt * 16 + (lane & 15);
    int mb = mt * 16 + ((lane >> 4) << 2);
    #pragma unroll
    for (int r = 0; r < 4; r++)
        Y2[(size_t)(mb + r) * 80 + n] = acc[r];
}

// Channel mixing; writes Zb as bf16 rows [m][96] (cols 80..95 zero).
__global__ void __launch_bounds__(256) k_mix(
    const float* Y2, __hip_bfloat16* Zb,
    const float* fw1, const float* fw2, int l)
{
    int gid = blockIdx.x * 256 + threadIdx.x;  // < 122880
    int col = gid % 96;
    int row = gid / 96;
    if (col >= 80) { Zb[gid] = __float2bfloat16(0.0f); return; }
    int ky = row % 20;
    int oc = (row / 20) % 32;
    int b = row / 640;
    int z = col & 1;
    int kxi = col >> 1;
    const float* wp;
    int x;
    if (kxi < 20) { wp = fw1; x = kxi; } else { wp = fw2; x = kxi - 20; }
    size_t wbase = ((((size_t)(l * 32) * 32 + oc) * 20 + x) * 20 + ky) * 2 + z;
    const float* y2 = Y2 + ((size_t)b * 32 * 20 + ky) * 80 + kxi * 2 + z;
    float acc = 0.f;
    for (int i = 0; i < 32; i++) {
        float yv = y2[(size_t)i * 1600];
        float wv = wp[wbase + (size_t)i * 25600];
        acc += yv * wv;
    }
    Zb[gid] = __float2bfloat16(acc);
}

// I1 as TRANSPOSED MFMA GEMM: U'[m'=(hh,part)][n'=(oc,ky)] = Ti1^T x Zb^T.
// A-operand = Ti1 table (same table as before — fragment mirror symmetry);
// B-operand = Zb rows via aligned 16B loads; C lands with (oc,ky,part) on the
// fast axis -> U2 fragment layout written in near-contiguous runs (the R11
// version scattered 2B stores across 4KB strides — suspected +45us).
__global__ void __launch_bounds__(256) k_I1mt(
    const __hip_bfloat16* Zb, const __hip_bfloat16* Ti1, __hip_bfloat16* U2)
{
    int wv = threadIdx.x >> 6, lane = threadIdx.x & 63;
    int task = blockIdx.x * 4 + wv;          // < 4800
    int b = task / 2400, rem = task % 2400;
    int mt = rem / 40, nt = rem % 40;        // mt: (hh,part)-tiles; nt: (oc,ky)-tiles
    int koff = (lane >> 4) << 3;
    int nrow = nt * 16 + (lane & 15);        // n' = oc*20 + ky
    const __hip_bfloat16* brow = Zb + ((size_t)b * 640 + nrow) * 96 + koff;
    f32x4 acc = {0.f, 0.f, 0.f, 0.f};
    #pragma unroll
    for (int kt = 0; kt < 3; kt++) {
        bf16x8 av = *reinterpret_cast<const bf16x8*>(Ti1 + (((mt * 3 + kt) << 9) + lane * 8));
        bf16x8 bv = *reinterpret_cast<const bf16x8*>(brow + kt * 32);
        acc = __builtin_amdgcn_mfma_f32_16x16x32_bf16(av, bv, acc, 0, 0, 0);
    }
    int oc = nrow / 20, ky = nrow % 20;
    int mbase = mt * 16 + ((lane >> 4) << 2);
    #pragma unroll
    for (int r = 0; r < 4; r++) {
        int m = mbase + r;
        int hh = m >> 1, part = m & 1;
        U2[(((size_t)b * HD + hh) * 32 + oc) * 64 + ky * 2 + part] =
            __float2bfloat16(acc[r]);
    }
}

// I2 as pure LDS-free GEMM per (b,h): Anew[oc][w] = act(U-DFT + conv + bias).
// U A-frags: aligned 16B loads from U2 block. Conv B-frags: aligned 16B loads
// from pixel-major A2in. Outputs: planar A (for F1m, l<3) + pixel-major A2out.
__global__ void __launch_bounds__(256) k_I2m(
    const __hip_bfloat16* U2, const __hip_bfloat16* A2in,
    __hip_bfloat16* A, __hip_bfloat16* A2out,
    const float* convw, const float* convb,
    const __hip_bfloat16* TinvF,
    int l, int do_gelu, int write_planar)
{
    int tid = threadIdx.x;
    int wv = tid >> 6, lane = tid & 63;
    int bh = blockIdx.x;                 // b*480 + h
    int b = bh / HD, h = bh % HD;
    int mrow = lane & 15, koff = (lane >> 4) << 3;
    int ocq = (lane >> 4) << 2;
    bf16x8 uf[2][2], wf[2];
    float bias[2][4];
    const __hip_bfloat16* U2b = U2 + (size_t)bh * 32 * 64;
    #pragma unroll
    for (int mt = 0; mt < 2; mt++) {
        int oc = mt * 16 + mrow;
        #pragma unroll
        for (int kt = 0; kt < 2; kt++)
            uf[mt][kt] = *reinterpret_cast<const bf16x8*>(U2b + oc * 64 + kt * 32 + koff);
        bf16x8 wvv;
        #pragma unroll
        for (int j = 0; j < 8; j++)
            wvv[j] = bf16s(convw[(size_t)l * 1024 + oc * 32 + koff + j]);
        wf[mt] = wvv;
        #pragma unroll
        for (int r = 0; r < 4; r++)
            bias[mt][r] = convb[l * 32 + mt * 16 + ocq + r];
    }
    const __hip_bfloat16* A2r = A2in + (size_t)bh * WD * 32;
    for (int i = 0; i < 15; i++) {
        int t = wv + 4 * i;
        int mt = t & 1, nt = t >> 1;
        f32x4 acc = {0.f, 0.f, 0.f, 0.f};
        #pragma unroll
        for (int kt = 0; kt < 2; kt++) {
            bf16x8 bv = *reinterpret_cast<const bf16x8*>(TinvF + (((nt * 2 + kt) << 9) + lane * 8));
            acc = __builtin_amdgcn_mfma_f32_16x16x32_bf16(uf[mt][kt], bv, acc, 0, 0, 0);
        }
        bf16x8 bv2 = *reinterpret_cast<const bf16x8*>(A2r + ((nt * 16 + mrow) << 5) + koff);
        acc = __builtin_amdgcn_mfma_f32_16x16x32_bf16(wf[mt], bv2, acc, 0, 0, 0);
        int w = nt * 16 + mrow;
        int ocb = mt * 16 + ocq;
        unsigned short us[4];
        #pragma unroll
        for (int r = 0; r < 4; r++) {
            float v = acc[r] + bias[mt][r];
            if (do_gelu) v = gelu_f(v);
            us[r] = (unsigned short)bf16s(v);
            if (write_planar)
                A[((size_t)b * CD + (ocb + r)) * PLANE + (size_t)h * WD + w] =
                    __float2bfloat16(v);
        }
        uint2 pk;
        pk.x = (unsigned)us[0] | ((unsigned)us[1] << 16);
        pk.y = (unsigned)us[2] | ((unsigned)us[3] << 16);
        *reinterpret_cast<uint2*>(A2out + (((size_t)bh * WD + w) << 5) + ocb) = pk;
    }
}

// Final: proj MLP + 3x3 mask conv + field*mask + pred. Reads pixel-major A2.
__global__ void __launch_bounds__(256) k_out(
    const __hip_bfloat16* A2fin, const float* inp, const float* src,
    const float* pw1, const float* pb1,
    const float* pw2, const float* pb2,
    const float* mw, const float* mb,
    float* out)
{
    __shared__ float sW1[CD * HALFD], sB1[HALFD], sW2[HALFD * 2], sB2[2], sM[9], sMB[1];
    int tid = threadIdx.x;
    for (int t = tid; t < CD * HALFD; t += 256) sW1[t] = pw1[t];
    if (tid < 16) sB1[tid] = pb1[tid];
    if (tid >= 32 && tid < 64) sW2[tid - 32] = pw2[tid - 32];
    if (tid >= 64 && tid < 66) sB2[tid - 64] = pb2[tid - 64];
    if (tid >= 96 && tid < 105) sM[tid - 96] = mw[tid - 96];
    if (tid == 128) sMB[0] = mb[0];
    __syncthreads();
    int gid = blockIdx.x * 256 + tid;  // < 460800
    int b = gid / PLANE;
    int r = gid % PLANE;
    int h = r / WD, w = r % WD;
    const bf16x8* ap = reinterpret_cast<const bf16x8*>(A2fin + (size_t)gid * 32);
    float av[32];
    #pragma unroll
    for (int q = 0; q < 4; q++) {
        bf16x8 v = ap[q];
        #pragma unroll
        for (int j = 0; j < 8; j++) av[q * 8 + j] = bfbits2f(v[j]);
    }
    float hid[16];
    #pragma unroll
    for (int j = 0; j < 16; j++) {
        float v = sB1[j];
        #pragma unroll
        for (int i = 0; i < 32; i++) v += av[i] * sW1[i * 16 + j];
        hid[j] = gelu_f(v);
    }
    float p0 = sB2[0], p1 = sB2[1];
    #pragma unroll
    for (int j = 0; j < 16; j++) { p0 += hid[j] * sW2[j * 2]; p1 += hid[j] * sW2[j * 2 + 1]; }
    float m = sMB[0];
    #pragma unroll
    for (int dh = 0; dh < 3; dh++) {
        int hh = h + dh - 1;
        #pragma unroll
        for (int dw = 0; dw < 3; dw++) {
            int ww = w + dw - 1;
            if (hh >= 0 && hh < HD && ww >= 0 && ww < WD)
                m += inp[(size_t)b * PLANE + (size_t)hh * WD + ww] * sM[dh * 3 + dw];
        }
    }
    float f0 = src[(size_t)gid * 3 + 1];
    float f1 = src[(size_t)gid * 3 + 2];
    out[(size_t)gid * 2 + 0] = f0 * m + p0;
    out[(size_t)gid * 2 + 1] = f1 * m + p1;
}

extern "C" void kernel_launch(void* const* d_in, const int* in_sizes, int n_in,
                              void* d_out, int out_size, void* d_ws, size_t ws_size,
                              hipStream_t stream) {
    const float* inp = (const float*)d_in[0];
    const float* src = (const float*)d_in[1];
    const float* iw1 = (const float*)d_in[2];
    const float* ib1 = (const float*)d_in[3];
    const float* iw2 = (const float*)d_in[4];
    const float* ib2 = (const float*)d_in[5];
    const float* ew1 = (const float*)d_in[6];
    const float* eb1 = (const float*)d_in[7];
    const float* ew2 = (const float*)d_in[8];
    const float* eb2 = (const float*)d_in[9];
    const float* fw1 = (const float*)d_in[10];
    const float* fw2 = (const float*)d_in[11];
    const float* cw  = (const float*)d_in[12];
    const float* cb  = (const float*)d_in[13];
    const float* pw1 = (const float*)d_in[14];
    const float* pb1 = (const float*)d_in[15];
    const float* pw2 = (const float*)d_in[16];
    const float* pb2 = (const float*)d_in[17];
    const float* mw  = (const float*)d_in[18];
    const float* mb  = (const float*)d_in[19];

    // Workspace (~125.5 MB; ws is 256 MiB per fillBuffer evidence):
    //   A planar bf16 | E planar bf16 | A2a, A2b pixel-major bf16 (ping-pong)
    //   | Y1 bf16 | Y2 f32 | Zb bf16 | U2 bf16 [bh][32][64] | tables bf16
    const size_t NA = (size_t)BD * CD * PLANE;
    __hip_bfloat16* A   = (__hip_bfloat16*)d_ws;
    __hip_bfloat16* E   = A + NA;
    __hip_bfloat16* A2a = E + NA;
    __hip_bfloat16* A2b = A2a + NA;
    __hip_bfloat16* Y1  = A2b + NA;
    float* Y2 = (float*)(Y1 + (size_t)BD * CD * WND * HD * 2);
    __hip_bfloat16* Zb = (__hip_bfloat16*)(Y2 + 1280 * 80);
    __hip_bfloat16* U2 = Zb + 1280 * 96;
    __hip_bfloat16* Tbl   = U2 + (size_t)BD * HD * 32 * 64;
    __hip_bfloat16* Twig  = Tbl;
    __hip_bfloat16* TinvF = Twig + 45 * 512;
    __hip_bfloat16* Tf2   = TinvF + 60 * 512;
    __hip_bfloat16* Ti1   = Tf2 + 150 * 512;

    k_tables<<<870, 256, 0, stream>>>(Tbl);
    k_ae<<<1800, 256, 0, stream>>>(src, inp, iw1, ib1, iw2, ib2,
                                   ew1, eb1, ew2, eb2, A, A2a, E);

    __hip_bfloat16* ping[2] = {A2a, A2b};
    for (int l = 0; l < 4; l++) {
        k_F1m<<<1440, 256, 0, stream>>>(A, E, Twig, Y1);
        k_F2m<<<100, 256, 0, stream>>>(Y1, Tf2, Y2);
        k_mix<<<480, 256, 0, stream>>>(Y2, Zb, fw1, fw2, l);
        k_I1mt<<<1200, 256, 0, stream>>>(Zb, Ti1, U2);
        k_I2m<<<BD * HD, 256, 0, stream>>>(U2, ping[l & 1], A, ping[(l + 1) & 1],
                                           cw, cb, TinvF,
                                           l, (l < 3) ? 1 : 0, (l < 3) ? 1 : 0);
    }
    k_out<<<1800, 256, 0, stream>>>(ping[0], inp, src, pw1, pb1, pw2, pb2, mw, mb,
                                    (float*)d_out);
}

// Round 13
// 489.719 us; speedup vs baseline: 1.0574x; 1.0395x over previous
//
#include <hip/hip_runtime.h>
#include <hip/hip_bf16.h>

#define BD 2
#define HD 480
#define WD 480
#define CD 32
#define HALFD 16
#define WND 20
#define NP 500
#define PLANE (HD*WD)
#define TWO_PI_OVER_NP 0.012566370614359172954f  /* 2*pi/500 */

typedef __attribute__((ext_vector_type(8))) short bf16x8;
typedef __attribute__((ext_vector_type(4))) float f32x4;

__device__ __forceinline__ float gelu_f(float x) {
    return 0.5f * x * (1.0f + erff(x * 0.70710678118654752f));
}
__device__ __forceinline__ float bfbits2f(short s) {
    unsigned u = ((unsigned)(unsigned short)s) << 16;
    return __uint_as_float(u);
}
__device__ __forceinline__ short bf16s(float v) {
    __hip_bfloat16 b = __float2bfloat16(v);
    return *reinterpret_cast<short*>(&b);
}

// Input MLPs: a -> A (planar) + A2 (pixel-major); e -> E (planar, layer-invariant).
__global__ void __launch_bounds__(256) k_ae(
    const float* src, const float* inp,
    const float* iw1, const float* ib1,
    const float* iw2, const float* ib2,
    const float* ew1, const float* eb1,
    const float* ew2, const float* eb2,
    __hip_bfloat16* A, __hip_bfloat16* A2, __hip_bfloat16* E)
{
    __shared__ float s_iw1[80], s_ib1[16], s_iw2[512], s_ib2[32];
    __shared__ float s_ew1[48], s_eb1[16], s_ew2[512], s_eb2[32];
    int tid = threadIdx.x;
    for (int t = tid; t < 512; t += 256) s_iw2[t] = iw2[t];
    for (int t = tid; t < 512; t += 256) s_ew2[t] = ew2[t];
    if (tid < 80) s_iw1[tid] = iw1[tid];
    if (tid >= 96 && tid < 112) s_ib1[tid - 96] = ib1[tid - 96];
    if (tid >= 128 && tid < 160) s_ib2[tid - 128] = ib2[tid - 128];
    if (tid >= 160 && tid < 208) s_ew1[tid - 160] = ew1[tid - 160];
    if (tid >= 208 && tid < 224) s_eb1[tid - 208] = eb1[tid - 208];
    if (tid >= 224 && tid < 256) s_eb2[tid - 224] = eb2[tid - 224];
    __syncthreads();
    int gid = blockIdx.x * 256 + tid;  // < 460800
    int b = gid / PLANE;
    int r = gid % PLANE;
    int h = r / WD, w = r % WD;
    float gx = (float)h * (1.0f / 479.0f);
    float gy = (float)w * (1.0f / 479.0f);
    float s0 = src[(size_t)gid * 3 + 0];
    float s1 = src[(size_t)gid * 3 + 1];
    float s2 = src[(size_t)gid * 3 + 2];
    float hid[16];
    #pragma unroll
    for (int j = 0; j < 16; j++) {
        float v = s_ib1[j] + s0 * s_iw1[j] + s1 * s_iw1[16 + j] + s2 * s_iw1[32 + j]
                + gx * s_iw1[48 + j] + gy * s_iw1[64 + j];
        hid[j] = gelu_f(v);
    }
    __hip_bfloat16* Ap = A + (size_t)b * CD * PLANE + r;
    unsigned pk[16];
    for (int c = 0; c < 32; c++) {
        float v = s_ib2[c];
        #pragma unroll
        for (int j = 0; j < 16; j++) v += hid[j] * s_iw2[j * 32 + c];
        Ap[(size_t)c * PLANE] = __float2bfloat16(v);
        unsigned short us = (unsigned short)bf16s(v);
        if (c & 1) pk[c >> 1] |= ((unsigned)us) << 16; else pk[c >> 1] = us;
    }
    uint4* A2p = reinterpret_cast<uint4*>(A2 + (size_t)gid * 32);
    #pragma unroll
    for (int q = 0; q < 4; q++)
        A2p[q] = make_uint4(pk[q * 4], pk[q * 4 + 1], pk[q * 4 + 2], pk[q * 4 + 3]);
    float xi = inp[gid];
    #pragma unroll
    for (int j = 0; j < 16; j++) {
        float v = s_eb1[j] + xi * s_ew1[j] + gx * s_ew1[16 + j] + gy * s_ew1[32 + j];
        hid[j] = gelu_f(v);
    }
    __hip_bfloat16* Ep = E + (size_t)b * CD * PLANE + r;
    for (int c = 0; c < 32; c++) {
        float e = s_eb2[c];
        #pragma unroll
        for (int j = 0; j < 16; j++) e += hid[j] * s_ew2[j * 32 + c];
        Ep[(size_t)c * PLANE] = __float2bfloat16(e);
    }
}

// All four swizzled twiddle fragment tables:
// Twig[0,45) | TinvF[45,105) | Tf2[105,255) | Ti1[255,435).
__global__ void k_tables(__hip_bfloat16* T) {
    int e = blockIdx.x * 256 + threadIdx.x;   // < 435*512
    if (e >= 435 * 512) return;
    int tile = e >> 9, r = e & 511;
    int lane = r >> 3, j = r & 7;
    float v = 0.0f;
    if (tile < 45) {                       // Twig: F1 row-DFT (K=480, N=48 pad)
        int kt = tile / 3, nt = tile % 3;
        int k = kt * 32 + ((lane >> 4) << 3) + j;
        int n = nt * 16 + (lane & 15);
        if (n < 40) {
            int ky = n >> 1;
            int idx = (k * ky) % NP;
            float ang = (float)idx * TWO_PI_OVER_NP;
            v = (n & 1) ? -sinf(ang) : cosf(ang);
        }
    } else if (tile < 105) {               // TinvF: I2 inverse-ky (K=64 pad, N=480), scale baked
        int t2 = tile - 45;
        int nt = t2 >> 1, kt = t2 & 1;
        int kk = kt * 32 + ((lane >> 4) << 3) + j;
        int w = nt * 16 + (lane & 15);
        if (kk < 40) {
            int ky = kk >> 1;
            int idx = (ky * w) % NP;
            float ang = (float)idx * TWO_PI_OVER_NP;
            float sc = (ky == 0 ? 1.0f : 2.0f) * (1.0f / 250000.0f);
            v = ((kk & 1) ? -sinf(ang) : cosf(ang)) * sc;
        }
    } else if (tile < 255) {               // Tf2: F2 h-DFT (K=960, N=80)
        int t2 = tile - 105;
        int kt = t2 / 5, nt = t2 % 5;
        int k = kt * 32 + ((lane >> 4) << 3) + j;
        int n = nt * 16 + (lane & 15);
        int hh = k >> 1, ri = k & 1;
        int kxi = n >> 1, part = n & 1;
        int kx = (kxi < 20) ? kxi : kxi + 460;
        int idx = (kx * hh) % NP;
        float ang = (float)idx * TWO_PI_OVER_NP;
        float c = cosf(ang), s = sinf(ang);
        v = (part == 0) ? (ri == 0 ? c : s) : (ri == 0 ? -s : c);
    } else {                               // Ti1: (hh,part)-major, K=(kxi,ri) pad 96
        int t2 = tile - 255;
        int nt = t2 / 3, kt = t2 % 3;
        int k = kt * 32 + ((lane >> 4) << 3) + j;
        int n = nt * 16 + (lane & 15);
        if (k < 80) {
            int kxi = k >> 1, ri = k & 1;
            int hh = n >> 1, part = n & 1;
            int kx = (kxi < 20) ? kxi : kxi + 460;
            int idx = (kx * hh) % NP;
            float ang = (float)idx * TWO_PI_OVER_NP;
            float c = cosf(ang), s = sinf(ang);
            v = (part == 0) ? (ri == 0 ? c : -s) : (ri == 0 ? s : c);
        }
    }
    T[e] = __float2bfloat16(v);
}

// F1 as pure global-operand MFMA GEMM; A-fragment formed on the fly as A ⊙ E.
__global__ void __launch_bounds__(256) k_F1m(
    const __hip_bfloat16* A, const __hip_bfloat16* E,
    const __hip_bfloat16* Twig, __hip_bfloat16* Y1)
{
    int wv = threadIdx.x >> 6, lane = threadIdx.x & 63;
    int task = blockIdx.x * 4 + wv;          // < 5760
    int bh = task / 6, rem = task % 6;
    int mt = rem & 1, nt = rem >> 1;
    int b = bh / HD, h = bh % HD;
    int c = mt * 16 + (lane & 15);
    int koff = (lane >> 4) << 3;
    size_t base = ((size_t)(b * 32 + c)) * PLANE + (size_t)h * WD + koff;
    const __hip_bfloat16* arow = A + base;
    const __hip_bfloat16* erow = E + base;
    f32x4 acc = {0.f, 0.f, 0.f, 0.f};
    #pragma unroll
    for (int kt = 0; kt < 15; kt++) {
        bf16x8 av = *reinterpret_cast<const bf16x8*>(arow + kt * 32);
        bf16x8 ev = *reinterpret_cast<const bf16x8*>(erow + kt * 32);
        bf16x8 gv;
        #pragma unroll
        for (int j = 0; j < 8; j++)
            gv[j] = bf16s(bfbits2f(av[j]) * bfbits2f(ev[j]));
        bf16x8 bv = *reinterpret_cast<const bf16x8*>(Twig + (((kt * 3 + nt) << 9) + lane * 8));
        acc = __builtin_amdgcn_mfma_f32_16x16x32_bf16(gv, bv, acc, 0, 0, 0);
    }
    int n = nt * 16 + (lane & 15);
    if (n < 40) {
        int ky = n >> 1, part = n & 1;
        int crow = mt * 16 + ((lane >> 4) << 2);
        #pragma unroll
        for (int r = 0; r < 4; r++) {
            int cc = crow + r;
            Y1[((((size_t)(b * 32 + cc)) * WND + ky) * HD + h) * 2 + part] =
                __float2bfloat16(acc[r]);
        }
    }
}

// F2 as MFMA GEMM: M=1280 rows, K=960, N=80.
__global__ void __launch_bounds__(256) k_F2m(
    const __hip_bfloat16* Y1, const __hip_bfloat16* Tf2, float* Y2)
{
    int wv = threadIdx.x >> 6, lane = threadIdx.x & 63;
    int task = blockIdx.x * 4 + wv;          // < 400
    int mt = task / 5, nt = task % 5;
    int row = mt * 16 + (lane & 15);
    int koff = (lane >> 4) << 3;
    const __hip_bfloat16* arow = Y1 + (size_t)row * 960 + koff;
    f32x4 acc = {0.f, 0.f, 0.f, 0.f};
    #pragma unroll
    for (int kt = 0; kt < 30; kt++) {
        bf16x8 av = *reinterpret_cast<const bf16x8*>(arow + kt * 32);
        bf16x8 bv = *reinterpret_cast<const bf16x8*>(Tf2 + (((kt * 5 + nt) << 9) + lane * 8));
        acc = __builtin_amdgcn_mfma_f32_16x16x32_bf16(av, bv, acc, 0, 0, 0);
    }
    int n = nt * 16 + (lane & 15);
    int mb = mt * 16 + ((lane >> 4) << 2);
    #pragma unroll
    for (int r = 0; r < 4; r++)
        Y2[(size_t)(mb + r) * 80 + n] = acc[r];
}

// Channel mixing; writes Zb as bf16 rows [m][96] (cols 80..95 zero).
__global__ void __launch_bounds__(256) k_mix(
    const float* Y2, __hip_bfloat16* Zb,
    const float* fw1, const float* fw2, int l)
{
    int gid = blockIdx.x * 256 + threadIdx.x;  // < 122880
    int col = gid % 96;
    int row = gid / 96;
    if (col >= 80) { Zb[gid] = __float2bfloat16(0.0f); return; }
    int ky = row % 20;
    int oc = (row / 20) % 32;
    int b = row / 640;
    int z = col & 1;
    int kxi = col >> 1;
    const float* wp;
    int x;
    if (kxi < 20) { wp = fw1; x = kxi; } else { wp = fw2; x = kxi - 20; }
    size_t wbase = ((((size_t)(l * 32) * 32 + oc) * 20 + x) * 20 + ky) * 2 + z;
    const float* y2 = Y2 + ((size_t)b * 32 * 20 + ky) * 80 + kxi * 2 + z;
    float acc = 0.f;
    for (int i = 0; i < 32; i++) {
        float yv = y2[(size_t)i * 1600];
        float wv = wp[wbase + (size_t)i * 25600];
        acc += yv * wv;
    }
    Zb[gid] = __float2bfloat16(acc);
}

// I1 as transposed MFMA GEMM: U'[(hh,part)][(oc,ky)] = Ti1^T x Zb^T.
__global__ void __launch_bounds__(256) k_I1mt(
    const __hip_bfloat16* Zb, const __hip_bfloat16* Ti1, __hip_bfloat16* U2)
{
    int wv = threadIdx.x >> 6, lane = threadIdx.x & 63;
    int task = blockIdx.x * 4 + wv;          // < 4800
    int b = task / 2400, rem = task % 2400;
    int mt = rem / 40, nt = rem % 40;
    int koff = (lane >> 4) << 3;
    int nrow = nt * 16 + (lane & 15);        // n' = oc*20 + ky
    const __hip_bfloat16* brow = Zb + ((size_t)b * 640 + nrow) * 96 + koff;
    f32x4 acc = {0.f, 0.f, 0.f, 0.f};
    #pragma unroll
    for (int kt = 0; kt < 3; kt++) {
        bf16x8 av = *reinterpret_cast<const bf16x8*>(Ti1 + (((mt * 3 + kt) << 9) + lane * 8));
        bf16x8 bv = *reinterpret_cast<const bf16x8*>(brow + kt * 32);
        acc = __builtin_amdgcn_mfma_f32_16x16x32_bf16(av, bv, acc, 0, 0, 0);
    }
    int oc = nrow / 20, ky = nrow % 20;
    int mbase = mt * 16 + ((lane >> 4) << 2);
    #pragma unroll
    for (int r = 0; r < 4; r++) {
        int m = mbase + r;
        int hh = m >> 1, part = m & 1;
        U2[(((size_t)b * HD + hh) * 32 + oc) * 64 + ky * 2 + part] =
            __float2bfloat16(acc[r]);
    }
}

// I2 split 3x finer than R12: task = (bh, mt, nt-group), 11520 wave-tasks
// (vs 3840) so the serial global-load->MFMA chain per wave is 1/3 as long and
// 3x more waves hide latency. Prefetch is per-mt only (2x16B U2 + 8 convw).
__global__ void __launch_bounds__(256) k_I2s(
    const __hip_bfloat16* U2, const __hip_bfloat16* A2in,
    __hip_bfloat16* A, __hip_bfloat16* A2out,
    const float* convw, const float* convb,
    const __hip_bfloat16* TinvF,
    int l, int do_gelu, int write_planar)
{
    int tid = threadIdx.x;
    int wv = tid >> 6, lane = tid & 63;
    int task = blockIdx.x * 4 + wv;      // < 11520
    int bh = task / 12, rem = task % 12;
    int mt = rem & 1, ntg = rem >> 1;    // ntg in [0,6): tiles nt = ntg*5 .. +5
    int b = bh / HD, h = bh % HD;
    int mrow = lane & 15, koff = (lane >> 4) << 3;
    int ocq = (lane >> 4) << 2;
    int oc = mt * 16 + mrow;
    const __hip_bfloat16* U2b = U2 + (size_t)bh * 32 * 64;
    bf16x8 uf0 = *reinterpret_cast<const bf16x8*>(U2b + oc * 64 + koff);
    bf16x8 uf1 = *reinterpret_cast<const bf16x8*>(U2b + oc * 64 + 32 + koff);
    bf16x8 wf;
    #pragma unroll
    for (int j = 0; j < 8; j++)
        wf[j] = bf16s(convw[(size_t)l * 1024 + oc * 32 + koff + j]);
    float bias[4];
    #pragma unroll
    for (int r = 0; r < 4; r++)
        bias[r] = convb[l * 32 + mt * 16 + ocq + r];
    const __hip_bfloat16* A2r = A2in + (size_t)bh * WD * 32;
    #pragma unroll
    for (int i = 0; i < 5; i++) {
        int nt = ntg * 5 + i;
        f32x4 acc = {0.f, 0.f, 0.f, 0.f};
        bf16x8 bv0 = *reinterpret_cast<const bf16x8*>(TinvF + (((nt * 2) << 9) + lane * 8));
        acc = __builtin_amdgcn_mfma_f32_16x16x32_bf16(uf0, bv0, acc, 0, 0, 0);
        bf16x8 bv1 = *reinterpret_cast<const bf16x8*>(TinvF + (((nt * 2 + 1) << 9) + lane * 8));
        acc = __builtin_amdgcn_mfma_f32_16x16x32_bf16(uf1, bv1, acc, 0, 0, 0);
        bf16x8 bv2 = *reinterpret_cast<const bf16x8*>(A2r + ((nt * 16 + mrow) << 5) + koff);
        acc = __builtin_amdgcn_mfma_f32_16x16x32_bf16(wf, bv2, acc, 0, 0, 0);
        int w = nt * 16 + mrow;
        int ocb = mt * 16 + ocq;
        unsigned short us[4];
        #pragma unroll
        for (int r = 0; r < 4; r++) {
            float v = acc[r] + bias[r];
            if (do_gelu) v = gelu_f(v);
            us[r] = (unsigned short)bf16s(v);
            if (write_planar)
                A[((size_t)b * CD + (ocb + r)) * PLANE + (size_t)h * WD + w] =
                    __float2bfloat16(v);
        }
        uint2 pk;
        pk.x = (unsigned)us[0] | ((unsigned)us[1] << 16);
        pk.y = (unsigned)us[2] | ((unsigned)us[3] << 16);
        *reinterpret_cast<uint2*>(A2out + (((size_t)bh * WD + w) << 5) + ocb) = pk;
    }
}

// Final: proj MLP + 3x3 mask conv + field*mask + pred. Reads pixel-major A2.
__global__ void __launch_bounds__(256) k_out(
    const __hip_bfloat16* A2fin, const float* inp, const float* src,
    const float* pw1, const float* pb1,
    const float* pw2, const float* pb2,
    const float* mw, const float* mb,
    float* out)
{
    __shared__ float sW1[CD * HALFD], sB1[HALFD], sW2[HALFD * 2], sB2[2], sM[9], sMB[1];
    int tid = threadIdx.x;
    for (int t = tid; t < CD * HALFD; t += 256) sW1[t] = pw1[t];
    if (tid < 16) sB1[tid] = pb1[tid];
    if (tid >= 32 && tid < 64) sW2[tid - 32] = pw2[tid - 32];
    if (tid >= 64 && tid < 66) sB2[tid - 64] = pb2[tid - 64];
    if (tid >= 96 && tid < 105) sM[tid - 96] = mw[tid - 96];
    if (tid == 128) sMB[0] = mb[0];
    __syncthreads();
    int gid = blockIdx.x * 256 + tid;  // < 460800
    int b = gid / PLANE;
    int r = gid % PLANE;
    int h = r / WD, w = r % WD;
    const bf16x8* ap = reinterpret_cast<const bf16x8*>(A2fin + (size_t)gid * 32);
    float av[32];
    #pragma unroll
    for (int q = 0; q < 4; q++) {
        bf16x8 v = ap[q];
        #pragma unroll
        for (int j = 0; j < 8; j++) av[q * 8 + j] = bfbits2f(v[j]);
    }
    float hid[16];
    #pragma unroll
    for (int j = 0; j < 16; j++) {
        float v = sB1[j];
        #pragma unroll
        for (int i = 0; i < 32; i++) v += av[i] * sW1[i * 16 + j];
        hid[j] = gelu_f(v);
    }
    float p0 = sB2[0], p1 = sB2[1];
    #pragma unroll
    for (int j = 0; j < 16; j++) { p0 += hid[j] * sW2[j * 2]; p1 += hid[j] * sW2[j * 2 + 1]; }
    float m = sMB[0];
    #pragma unroll
    for (int dh = 0; dh < 3; dh++) {
        int hh = h + dh - 1;
        #pragma unroll
        for (int dw = 0; dw < 3; dw++) {
            int ww = w + dw - 1;
            if (hh >= 0 && hh < HD && ww >= 0 && ww < WD)
                m += inp[(size_t)b * PLANE + (size_t)hh * WD + ww] * sM[dh * 3 + dw];
        }
    }
    float f0 = src[(size_t)gid * 3 + 1];
    float f1 = src[(size_t)gid * 3 + 2];
    out[(size_t)gid * 2 + 0] = f0 * m + p0;
    out[(size_t)gid * 2 + 1] = f1 * m + p1;
}

extern "C" void kernel_launch(void* const* d_in, const int* in_sizes, int n_in,
                              void* d_out, int out_size, void* d_ws, size_t ws_size,
                              hipStream_t stream) {
    const float* inp = (const float*)d_in[0];
    const float* src = (const float*)d_in[1];
    const float* iw1 = (const float*)d_in[2];
    const float* ib1 = (const float*)d_in[3];
    const float* iw2 = (const float*)d_in[4];
    const float* ib2 = (const float*)d_in[5];
    const float* ew1 = (const float*)d_in[6];
    const float* eb1 = (const float*)d_in[7];
    const float* ew2 = (const float*)d_in[8];
    const float* eb2 = (const float*)d_in[9];
    const float* fw1 = (const float*)d_in[10];
    const float* fw2 = (const float*)d_in[11];
    const float* cw  = (const float*)d_in[12];
    const float* cb  = (const float*)d_in[13];
    const float* pw1 = (const float*)d_in[14];
    const float* pb1 = (const float*)d_in[15];
    const float* pw2 = (const float*)d_in[16];
    const float* pb2 = (const float*)d_in[17];
    const float* mw  = (const float*)d_in[18];
    const float* mb  = (const float*)d_in[19];

    // Workspace (~125.5 MB):
    //   A planar bf16 | E planar bf16 | A2a, A2b pixel-major bf16 (ping-pong)
    //   | Y1 bf16 | Y2 f32 | Zb bf16 | U2 bf16 [bh][32][64] | tables bf16
    const size_t NA = (size_t)BD * CD * PLANE;
    __hip_bfloat16* A   = (__hip_bfloat16*)d_ws;
    __hip_bfloat16* E   = A + NA;
    __hip_bfloat16* A2a = E + NA;
    __hip_bfloat16* A2b = A2a + NA;
    __hip_bfloat16* Y1  = A2b + NA;
    float* Y2 = (float*)(Y1 + (size_t)BD * CD * WND * HD * 2);
    __hip_bfloat16* Zb = (__hip_bfloat16*)(Y2 + 1280 * 80);
    __hip_bfloat16* U2 = Zb + 1280 * 96;
    __hip_bfloat16* Tbl   = U2 + (size_t)BD * HD * 32 * 64;
    __hip_bfloat16* Twig  = Tbl;
    __hip_bfloat16* TinvF = Twig + 45 * 512;
    __hip_bfloat16* Tf2   = TinvF + 60 * 512;
    __hip_bfloat16* Ti1   = Tf2 + 150 * 512;

    k_tables<<<870, 256, 0, stream>>>(Tbl);
    k_ae<<<1800, 256, 0, stream>>>(src, inp, iw1, ib1, iw2, ib2,
                                   ew1, eb1, ew2, eb2, A, A2a, E);

    __hip_bfloat16* ping[2] = {A2a, A2b};
    for (int l = 0; l < 4; l++) {
        k_F1m<<<1440, 256, 0, stream>>>(A, E, Twig, Y1);
        k_F2m<<<100, 256, 0, stream>>>(Y1, Tf2, Y2);
        k_mix<<<480, 256, 0, stream>>>(Y2, Zb, fw1, fw2, l);
        k_I1mt<<<1200, 256, 0, stream>>>(Zb, Ti1, U2);
        k_I2s<<<2880, 256, 0, stream>>>(U2, ping[l & 1], A, ping[(l + 1) & 1],
                                        cw, cb, TinvF,
                                        l, (l < 3) ? 1 : 0, (l < 3) ? 1 : 0);
    }
    k_out<<<1800, 256, 0, stream>>>(ping[0], inp, src, pw1, pb1, pw2, pb2, mw, mb,
                                    (float*)d_out);
}

// Round 14
// 461.106 us; speedup vs baseline: 1.1231x; 1.0621x over previous
//
#include <hip/hip_runtime.h>
#include <hip/hip_bf16.h>

#define BD 2
#define HD 480
#define WD 480
#define CD 32
#define HALFD 16
#define WND 20
#define NP 500
#define PLANE (HD*WD)
#define TWO_PI_OVER_NP 0.012566370614359172954f  /* 2*pi/500 */

typedef __attribute__((ext_vector_type(8))) short bf16x8;
typedef __attribute__((ext_vector_type(4))) float f32x4;

__device__ __forceinline__ float gelu_f(float x) {
    return 0.5f * x * (1.0f + erff(x * 0.70710678118654752f));
}
__device__ __forceinline__ float bfbits2f(short s) {
    unsigned u = ((unsigned)(unsigned short)s) << 16;
    return __uint_as_float(u);
}
__device__ __forceinline__ short bf16s(float v) {
    __hip_bfloat16 b = __float2bfloat16(v);
    return *reinterpret_cast<short*>(&b);
}

// Input MLPs. Outputs: A2 pixel-major [pix][32], E2 pixel-major [pix][32],
// G3 row-block [bh][c][480] = a*e (the DFT operand layout F1m consumes).
__global__ void __launch_bounds__(256) k_ae(
    const float* src, const float* inp,
    const float* iw1, const float* ib1,
    const float* iw2, const float* ib2,
    const float* ew1, const float* eb1,
    const float* ew2, const float* eb2,
    __hip_bfloat16* A2, __hip_bfloat16* E2, __hip_bfloat16* G3)
{
    __shared__ float s_iw1[80], s_ib1[16], s_iw2[512], s_ib2[32];
    __shared__ float s_ew1[48], s_eb1[16], s_ew2[512], s_eb2[32];
    int tid = threadIdx.x;
    for (int t = tid; t < 512; t += 256) s_iw2[t] = iw2[t];
    for (int t = tid; t < 512; t += 256) s_ew2[t] = ew2[t];
    if (tid < 80) s_iw1[tid] = iw1[tid];
    if (tid >= 96 && tid < 112) s_ib1[tid - 96] = ib1[tid - 96];
    if (tid >= 128 && tid < 160) s_ib2[tid - 128] = ib2[tid - 128];
    if (tid >= 160 && tid < 208) s_ew1[tid - 160] = ew1[tid - 160];
    if (tid >= 208 && tid < 224) s_eb1[tid - 208] = eb1[tid - 208];
    if (tid >= 224 && tid < 256) s_eb2[tid - 224] = eb2[tid - 224];
    __syncthreads();
    int gid = blockIdx.x * 256 + tid;  // < 460800
    int bh = gid / WD;                 // b*480 + h
    int w = gid % WD;
    int b = gid / PLANE;
    int r = gid % PLANE;
    int h = r / WD;
    float gx = (float)h * (1.0f / 479.0f);
    float gy = (float)w * (1.0f / 479.0f);
    float s0 = src[(size_t)gid * 3 + 0];
    float s1 = src[(size_t)gid * 3 + 1];
    float s2 = src[(size_t)gid * 3 + 2];
    float hid[16];
    // e-MLP first: ev[] kept live for G3
    float xi = inp[gid];
    #pragma unroll
    for (int j = 0; j < 16; j++) {
        float v = s_eb1[j] + xi * s_ew1[j] + gx * s_ew1[16 + j] + gy * s_ew1[32 + j];
        hid[j] = gelu_f(v);
    }
    float ev[32];
    unsigned pk[16];
    for (int c = 0; c < 32; c++) {
        float e = s_eb2[c];
        #pragma unroll
        for (int j = 0; j < 16; j++) e += hid[j] * s_ew2[j * 32 + c];
        ev[c] = e;
        unsigned short us = (unsigned short)bf16s(e);
        if (c & 1) pk[c >> 1] |= ((unsigned)us) << 16; else pk[c >> 1] = us;
    }
    uint4* E2p = reinterpret_cast<uint4*>(E2 + (size_t)gid * 32);
    #pragma unroll
    for (int q = 0; q < 4; q++)
        E2p[q] = make_uint4(pk[q * 4], pk[q * 4 + 1], pk[q * 4 + 2], pk[q * 4 + 3]);
    // a-MLP; write A2 + G3 = a*e
    #pragma unroll
    for (int j = 0; j < 16; j++) {
        float v = s_ib1[j] + s0 * s_iw1[j] + s1 * s_iw1[16 + j] + s2 * s_iw1[32 + j]
                + gx * s_iw1[48 + j] + gy * s_iw1[64 + j];
        hid[j] = gelu_f(v);
    }
    __hip_bfloat16* Gp = G3 + (size_t)bh * 32 * 480 + w;
    for (int c = 0; c < 32; c++) {
        float v = s_ib2[c];
        #pragma unroll
        for (int j = 0; j < 16; j++) v += hid[j] * s_iw2[j * 32 + c];
        unsigned short us = (unsigned short)bf16s(v);
        if (c & 1) pk[c >> 1] |= ((unsigned)us) << 16; else pk[c >> 1] = us;
        Gp[c * 480] = __float2bfloat16(v * ev[c]);
    }
    uint4* A2p = reinterpret_cast<uint4*>(A2 + (size_t)gid * 32);
    #pragma unroll
    for (int q = 0; q < 4; q++)
        A2p[q] = make_uint4(pk[q * 4], pk[q * 4 + 1], pk[q * 4 + 2], pk[q * 4 + 3]);
}

// All four swizzled twiddle fragment tables:
// Twig[0,45) | TinvF[45,105) | Tf2[105,255) | Ti1[255,435).
__global__ void k_tables(__hip_bfloat16* T) {
    int e = blockIdx.x * 256 + threadIdx.x;   // < 435*512
    if (e >= 435 * 512) return;
    int tile = e >> 9, r = e & 511;
    int lane = r >> 3, j = r & 7;
    float v = 0.0f;
    if (tile < 45) {                       // Twig: F1 row-DFT (K=480, N=48 pad)
        int kt = tile / 3, nt = tile % 3;
        int k = kt * 32 + ((lane >> 4) << 3) + j;
        int n = nt * 16 + (lane & 15);
        if (n < 40) {
            int ky = n >> 1;
            int idx = (k * ky) % NP;
            float ang = (float)idx * TWO_PI_OVER_NP;
            v = (n & 1) ? -sinf(ang) : cosf(ang);
        }
    } else if (tile < 105) {               // TinvF: I2 inverse-ky (K=64 pad, N=480), scale baked
        int t2 = tile - 45;
        int nt = t2 >> 1, kt = t2 & 1;
        int kk = kt * 32 + ((lane >> 4) << 3) + j;
        int w = nt * 16 + (lane & 15);
        if (kk < 40) {
            int ky = kk >> 1;
            int idx = (ky * w) % NP;
            float ang = (float)idx * TWO_PI_OVER_NP;
            float sc = (ky == 0 ? 1.0f : 2.0f) * (1.0f / 250000.0f);
            v = ((kk & 1) ? -sinf(ang) : cosf(ang)) * sc;
        }
    } else if (tile < 255) {               // Tf2: F2 h-DFT (K=960, N=80)
        int t2 = tile - 105;
        int kt = t2 / 5, nt = t2 % 5;
        int k = kt * 32 + ((lane >> 4) << 3) + j;
        int n = nt * 16 + (lane & 15);
        int hh = k >> 1, ri = k & 1;
        int kxi = n >> 1, part = n & 1;
        int kx = (kxi < 20) ? kxi : kxi + 460;
        int idx = (kx * hh) % NP;
        float ang = (float)idx * TWO_PI_OVER_NP;
        float c = cosf(ang), s = sinf(ang);
        v = (part == 0) ? (ri == 0 ? c : s) : (ri == 0 ? -s : c);
    } else {                               // Ti1: (hh,part)-major, K=(kxi,ri) pad 96
        int t2 = tile - 255;
        int nt = t2 / 3, kt = t2 % 3;
        int k = kt * 32 + ((lane >> 4) << 3) + j;
        int n = nt * 16 + (lane & 15);
        if (k < 80) {
            int kxi = k >> 1, ri = k & 1;
            int hh = n >> 1, part = n & 1;
            int kx = (kxi < 20) ? kxi : kxi + 460;
            int idx = (kx * hh) % NP;
            float ang = (float)idx * TWO_PI_OVER_NP;
            float c = cosf(ang), s = sinf(ang);
            v = (part == 0) ? (ri == 0 ? c : -s) : (ri == 0 ? s : c);
        }
    }
    T[e] = __float2bfloat16(v);
}

// F1 as pure single-stream MFMA GEMM over G3 row-blocks.
__global__ void __launch_bounds__(256) k_F1m(
    const __hip_bfloat16* G3, const __hip_bfloat16* Twig, __hip_bfloat16* Y1)
{
    int wv = threadIdx.x >> 6, lane = threadIdx.x & 63;
    int task = blockIdx.x * 4 + wv;          // < 5760
    int bh = task / 6, rem = task % 6;
    int mt = rem & 1, nt = rem >> 1;
    int b = bh / HD, h = bh % HD;
    int c = mt * 16 + (lane & 15);
    int koff = (lane >> 4) << 3;
    const __hip_bfloat16* grow = G3 + ((size_t)bh * 32 + c) * 480 + koff;
    f32x4 acc = {0.f, 0.f, 0.f, 0.f};
    #pragma unroll
    for (int kt = 0; kt < 15; kt++) {
        bf16x8 av = *reinterpret_cast<const bf16x8*>(grow + kt * 32);
        bf16x8 bv = *reinterpret_cast<const bf16x8*>(Twig + (((kt * 3 + nt) << 9) + lane * 8));
        acc = __builtin_amdgcn_mfma_f32_16x16x32_bf16(av, bv, acc, 0, 0, 0);
    }
    int n = nt * 16 + (lane & 15);
    if (n < 40) {
        int ky = n >> 1, part = n & 1;
        int crow = mt * 16 + ((lane >> 4) << 2);
        #pragma unroll
        for (int r = 0; r < 4; r++) {
            int cc = crow + r;
            Y1[((((size_t)(b * 32 + cc)) * WND + ky) * HD + h) * 2 + part] =
                __float2bfloat16(acc[r]);
        }
    }
}

// F2 as MFMA GEMM: M=1280 rows, K=960, N=80.
__global__ void __launch_bounds__(256) k_F2m(
    const __hip_bfloat16* Y1, const __hip_bfloat16* Tf2, float* Y2)
{
    int wv = threadIdx.x >> 6, lane = threadIdx.x & 63;
    int task = blockIdx.x * 4 + wv;          // < 400
    int mt = task / 5, nt = task % 5;
    int row = mt * 16 + (lane & 15);
    int koff = (lane >> 4) << 3;
    const __hip_bfloat16* arow = Y1 + (size_t)row * 960 + koff;
    f32x4 acc = {0.f, 0.f, 0.f, 0.f};
    #pragma unroll
    for (int kt = 0; kt < 30; kt++) {
        bf16x8 av = *reinterpret_cast<const bf16x8*>(arow + kt * 32);
        bf16x8 bv = *reinterpret_cast<const bf16x8*>(Tf2 + (((kt * 5 + nt) << 9) + lane * 8));
        acc = __builtin_amdgcn_mfma_f32_16x16x32_bf16(av, bv, acc, 0, 0, 0);
    }
    int n = nt * 16 + (lane & 15);
    int mb = mt * 16 + ((lane >> 4) << 2);
    #pragma unroll
    for (int r = 0; r < 4; r++)
        Y2[(size_t)(mb + r) * 80 + n] = acc[r];
}

// Channel mixing; writes Zb as bf16 rows [m][96] (cols 80..95 zero).
__global__ void __launch_bounds__(256) k_mix(
    const float* Y2, __hip_bfloat16* Zb,
    const float* fw1, const float* fw2, int l)
{
    int gid = blockIdx.x * 256 + threadIdx.x;  // < 122880
    int col = gid % 96;
    int row = gid / 96;
    if (col >= 80) { Zb[gid] = __float2bfloat16(0.0f); return; }
    int ky = row % 20;
    int oc = (row / 20) % 32;
    int b = row / 640;
    int z = col & 1;
    int kxi = col >> 1;
    const float* wp;
    int x;
    if (kxi < 20) { wp = fw1; x = kxi; } else { wp = fw2; x = kxi - 20; }
    size_t wbase = ((((size_t)(l * 32) * 32 + oc) * 20 + x) * 20 + ky) * 2 + z;
    const float* y2 = Y2 + ((size_t)b * 32 * 20 + ky) * 80 + kxi * 2 + z;
    float acc = 0.f;
    for (int i = 0; i < 32; i++) {
        float yv = y2[(size_t)i * 1600];
        float wv = wp[wbase + (size_t)i * 25600];
        acc += yv * wv;
    }
    Zb[gid] = __float2bfloat16(acc);
}

// I1 as transposed MFMA GEMM: U'[(hh,part)][(oc,ky)] = Ti1^T x Zb^T.
__global__ void __launch_bounds__(256) k_I1mt(
    const __hip_bfloat16* Zb, const __hip_bfloat16* Ti1, __hip_bfloat16* U2)
{
    int wv = threadIdx.x >> 6, lane = threadIdx.x & 63;
    int task = blockIdx.x * 4 + wv;          // < 4800
    int b = task / 2400, rem = task % 2400;
    int mt = rem / 40, nt = rem % 40;
    int koff = (lane >> 4) << 3;
    int nrow = nt * 16 + (lane & 15);        // n' = oc*20 + ky
    const __hip_bfloat16* brow = Zb + ((size_t)b * 640 + nrow) * 96 + koff;
    f32x4 acc = {0.f, 0.f, 0.f, 0.f};
    #pragma unroll
    for (int kt = 0; kt < 3; kt++) {
        bf16x8 av = *reinterpret_cast<const bf16x8*>(Ti1 + (((mt * 3 + kt) << 9) + lane * 8));
        bf16x8 bv = *reinterpret_cast<const bf16x8*>(brow + kt * 32);
        acc = __builtin_amdgcn_mfma_f32_16x16x32_bf16(av, bv, acc, 0, 0, 0);
    }
    int oc = nrow / 20, ky = nrow % 20;
    int mbase = mt * 16 + ((lane >> 4) << 2);
    #pragma unroll
    for (int r = 0; r < 4; r++) {
        int m = mbase + r;
        int hh = m >> 1, part = m & 1;
        U2[(((size_t)b * HD + hh) * 32 + oc) * 64 + ky * 2 + part] =
            __float2bfloat16(acc[r]);
    }
}

// I2: fine-split GEMM tasks (11520 waves). Outputs A2out (8B packed) and,
// for l<3, G3 = Anew*e in row-block layout (e from E2 via one 8B load).
__global__ void __launch_bounds__(256) k_I2s(
    const __hip_bfloat16* U2, const __hip_bfloat16* A2in,
    const __hip_bfloat16* E2, __hip_bfloat16* G3, __hip_bfloat16* A2out,
    const float* convw, const float* convb,
    const __hip_bfloat16* TinvF,
    int l, int do_gelu, int do_g)
{
    int tid = threadIdx.x;
    int wv = tid >> 6, lane = tid & 63;
    int task = blockIdx.x * 4 + wv;      // < 11520
    int bh = task / 12, rem = task % 12;
    int mt = rem & 1, ntg = rem >> 1;    // ntg in [0,6): tiles nt = ntg*5 .. +5
    int mrow = lane & 15, koff = (lane >> 4) << 3;
    int ocq = (lane >> 4) << 2;
    int oc = mt * 16 + mrow;
    const __hip_bfloat16* U2b = U2 + (size_t)bh * 32 * 64;
    bf16x8 uf0 = *reinterpret_cast<const bf16x8*>(U2b + oc * 64 + koff);
    bf16x8 uf1 = *reinterpret_cast<const bf16x8*>(U2b + oc * 64 + 32 + koff);
    bf16x8 wf;
    #pragma unroll
    for (int j = 0; j < 8; j++)
        wf[j] = bf16s(convw[(size_t)l * 1024 + oc * 32 + koff + j]);
    float bias[4];
    #pragma unroll
    for (int r = 0; r < 4; r++)
        bias[r] = convb[l * 32 + mt * 16 + ocq + r];
    const __hip_bfloat16* A2r = A2in + (size_t)bh * WD * 32;
    #pragma unroll
    for (int i = 0; i < 5; i++) {
        int nt = ntg * 5 + i;
        f32x4 acc = {0.f, 0.f, 0.f, 0.f};
        bf16x8 bv0 = *reinterpret_cast<const bf16x8*>(TinvF + (((nt * 2) << 9) + lane * 8));
        acc = __builtin_amdgcn_mfma_f32_16x16x32_bf16(uf0, bv0, acc, 0, 0, 0);
        bf16x8 bv1 = *reinterpret_cast<const bf16x8*>(TinvF + (((nt * 2 + 1) << 9) + lane * 8));
        acc = __builtin_amdgcn_mfma_f32_16x16x32_bf16(uf1, bv1, acc, 0, 0, 0);
        bf16x8 bv2 = *reinterpret_cast<const bf16x8*>(A2r + ((nt * 16 + mrow) << 5) + koff);
        acc = __builtin_amdgcn_mfma_f32_16x16x32_bf16(wf, bv2, acc, 0, 0, 0);
        int w = nt * 16 + mrow;
        int ocb = mt * 16 + ocq;
        unsigned short us[4];
        float vv[4];
        #pragma unroll
        for (int r = 0; r < 4; r++) {
            float v = acc[r] + bias[r];
            if (do_gelu) v = gelu_f(v);
            vv[r] = v;
            us[r] = (unsigned short)bf16s(v);
        }
        uint2 pk;
        pk.x = (unsigned)us[0] | ((unsigned)us[1] << 16);
        pk.y = (unsigned)us[2] | ((unsigned)us[3] << 16);
        *reinterpret_cast<uint2*>(A2out + (((size_t)bh * WD + w) << 5) + ocb) = pk;
        if (do_g) {
            uint2 epk = *reinterpret_cast<const uint2*>(E2 + (((size_t)bh * WD + w) << 5) + ocb);
            float e0 = bfbits2f((short)(epk.x & 0xffff));
            float e1 = bfbits2f((short)(epk.x >> 16));
            float e2 = bfbits2f((short)(epk.y & 0xffff));
            float e3 = bfbits2f((short)(epk.y >> 16));
            __hip_bfloat16* Gp = G3 + ((size_t)bh * 32 + ocb) * 480 + w;
            Gp[0]         = __float2bfloat16(vv[0] * e0);
            Gp[480]       = __float2bfloat16(vv[1] * e1);
            Gp[960]       = __float2bfloat16(vv[2] * e2);
            Gp[1440]      = __float2bfloat16(vv[3] * e3);
        }
    }
}

// Final: proj MLP + 3x3 mask conv + field*mask + pred. Reads pixel-major A2.
__global__ void __launch_bounds__(256) k_out(
    const __hip_bfloat16* A2fin, const float* inp, const float* src,
    const float* pw1, const float* pb1,
    const float* pw2, const float* pb2,
    const float* mw, const float* mb,
    float* out)
{
    __shared__ float sW1[CD * HALFD], sB1[HALFD], sW2[HALFD * 2], sB2[2], sM[9], sMB[1];
    int tid = threadIdx.x;
    for (int t = tid; t < CD * HALFD; t += 256) sW1[t] = pw1[t];
    if (tid < 16) sB1[tid] = pb1[tid];
    if (tid >= 32 && tid < 64) sW2[tid - 32] = pw2[tid - 32];
    if (tid >= 64 && tid < 66) sB2[tid - 64] = pb2[tid - 64];
    if (tid >= 96 && tid < 105) sM[tid - 96] = mw[tid - 96];
    if (tid == 128) sMB[0] = mb[0];
    __syncthreads();
    int gid = blockIdx.x * 256 + tid;  // < 460800
    int b = gid / PLANE;
    int r = gid % PLANE;
    int h = r / WD, w = r % WD;
    const bf16x8* ap = reinterpret_cast<const bf16x8*>(A2fin + (size_t)gid * 32);
    float av[32];
    #pragma unroll
    for (int q = 0; q < 4; q++) {
        bf16x8 v = ap[q];
        #pragma unroll
        for (int j = 0; j < 8; j++) av[q * 8 + j] = bfbits2f(v[j]);
    }
    float hid[16];
    #pragma unroll
    for (int j = 0; j < 16; j++) {
        float v = sB1[j];
        #pragma unroll
        for (int i = 0; i < 32; i++) v += av[i] * sW1[i * 16 + j];
        hid[j] = gelu_f(v);
    }
    float p0 = sB2[0], p1 = sB2[1];
    #pragma unroll
    for (int j = 0; j < 16; j++) { p0 += hid[j] * sW2[j * 2]; p1 += hid[j] * sW2[j * 2 + 1]; }
    float m = sMB[0];
    #pragma unroll
    for (int dh = 0; dh < 3; dh++) {
        int hh = h + dh - 1;
        #pragma unroll
        for (int dw = 0; dw < 3; dw++) {
            int ww = w + dw - 1;
            if (hh >= 0 && hh < HD && ww >= 0 && ww < WD)
                m += inp[(size_t)b * PLANE + (size_t)hh * WD + ww] * sM[dh * 3 + dw];
        }
    }
    float f0 = src[(size_t)gid * 3 + 1];
    float f1 = src[(size_t)gid * 3 + 2];
    out[(size_t)gid * 2 + 0] = f0 * m + p0;
    out[(size_t)gid * 2 + 1] = f1 * m + p1;
}

extern "C" void kernel_launch(void* const* d_in, const int* in_sizes, int n_in,
                              void* d_out, int out_size, void* d_ws, size_t ws_size,
                              hipStream_t stream) {
    const float* inp = (const float*)d_in[0];
    const float* src = (const float*)d_in[1];
    const float* iw1 = (const float*)d_in[2];
    const float* ib1 = (const float*)d_in[3];
    const float* iw2 = (const float*)d_in[4];
    const float* ib2 = (const float*)d_in[5];
    const float* ew1 = (const float*)d_in[6];
    const float* eb1 = (const float*)d_in[7];
    const float* ew2 = (const float*)d_in[8];
    const float* eb2 = (const float*)d_in[9];
    const float* fw1 = (const float*)d_in[10];
    const float* fw2 = (const float*)d_in[11];
    const float* cw  = (const float*)d_in[12];
    const float* cb  = (const float*)d_in[13];
    const float* pw1 = (const float*)d_in[14];
    const float* pb1 = (const float*)d_in[15];
    const float* pw2 = (const float*)d_in[16];
    const float* pb2 = (const float*)d_in[17];
    const float* mw  = (const float*)d_in[18];
    const float* mb  = (const float*)d_in[19];

    // Workspace (~125.5 MB):
    //   G3 row-block bf16 [bh][32][480] | E2 pixel-major | A2a, A2b (ping-pong)
    //   | Y1 bf16 | Y2 f32 | Zb bf16 | U2 bf16 [bh][32][64] | tables bf16
    const size_t NA = (size_t)BD * CD * PLANE;
    __hip_bfloat16* G3  = (__hip_bfloat16*)d_ws;
    __hip_bfloat16* E2  = G3 + NA;
    __hip_bfloat16* A2a = E2 + NA;
    __hip_bfloat16* A2b = A2a + NA;
    __hip_bfloat16* Y1  = A2b + NA;
    float* Y2 = (float*)(Y1 + (size_t)BD * CD * WND * HD * 2);
    __hip_bfloat16* Zb = (__hip_bfloat16*)(Y2 + 1280 * 80);
    __hip_bfloat16* U2 = Zb + 1280 * 96;
    __hip_bfloat16* Tbl   = U2 + (size_t)BD * HD * 32 * 64;
    __hip_bfloat16* Twig  = Tbl;
    __hip_bfloat16* TinvF = Twig + 45 * 512;
    __hip_bfloat16* Tf2   = TinvF + 60 * 512;
    __hip_bfloat16* Ti1   = Tf2 + 150 * 512;

    k_tables<<<870, 256, 0, stream>>>(Tbl);
    k_ae<<<1800, 256, 0, stream>>>(src, inp, iw1, ib1, iw2, ib2,
                                   ew1, eb1, ew2, eb2, A2a, E2, G3);

    __hip_bfloat16* ping[2] = {A2a, A2b};
    for (int l = 0; l < 4; l++) {
        k_F1m<<<1440, 256, 0, stream>>>(G3, Twig, Y1);
        k_F2m<<<100, 256, 0, stream>>>(Y1, Tf2, Y2);
        k_mix<<<480, 256, 0, stream>>>(Y2, Zb, fw1, fw2, l);
        k_I1mt<<<1200, 256, 0, stream>>>(Zb, Ti1, U2);
        k_I2s<<<2880, 256, 0, stream>>>(U2, ping[l & 1], E2, G3, ping[(l + 1) & 1],
                                        cw, cb, TinvF,
                                        l, (l < 3) ? 1 : 0, (l < 3) ? 1 : 0);
    }
    k_out<<<1800, 256, 0, stream>>>(ping[0], inp, src, pw1, pb1, pw2, pb2, mw, mb,
                                    (float*)d_out);
}

// Round 15
// 460.444 us; speedup vs baseline: 1.1247x; 1.0014x over previous
//
#include <hip/hip_runtime.h>
#include <hip/hip_bf16.h>

#define BD 2
#define HD 480
#define WD 480
#define CD 32
#define HALFD 16
#define WND 20
#define NP 500
#define PLANE (HD*WD)
#define TWO_PI_OVER_NP 0.012566370614359172954f  /* 2*pi/500 */

typedef __attribute__((ext_vector_type(8))) short bf16x8;
typedef __attribute__((ext_vector_type(4))) float f32x4;

__device__ __forceinline__ float gelu_f(float x) {
    return 0.5f * x * (1.0f + erff(x * 0.70710678118654752f));
}
__device__ __forceinline__ float bfbits2f(short s) {
    unsigned u = ((unsigned)(unsigned short)s) << 16;
    return __uint_as_float(u);
}
__device__ __forceinline__ short bf16s(float v) {
    __hip_bfloat16 b = __float2bfloat16(v);
    return *reinterpret_cast<short*>(&b);
}

// Input MLPs, MFMA form. One block per bh row (960 blocks).
// Phase 1 (VALU): hidden layers only -> LDS hidA/hidE[480][16] bf16.
// Phase 2 (MFMA): output 16->32 layers as GEMM (weights = A-operand in regs,
// zero-padded K 16->32). Outputs: A2/E2 pixel-major (8B contiguous stores),
// G3 row-block = a*e.
__global__ void __launch_bounds__(256) k_ae2(
    const float* src, const float* inp,
    const float* iw1, const float* ib1,
    const float* iw2, const float* ib2,
    const float* ew1, const float* eb1,
    const float* ew2, const float* eb2,
    __hip_bfloat16* A2, __hip_bfloat16* E2, __hip_bfloat16* G3)
{
    __shared__ __align__(16) __hip_bfloat16 hidA[480 * 16];
    __shared__ __align__(16) __hip_bfloat16 hidE[480 * 16];
    __shared__ float s_iw1[80], s_ib1[16], s_ew1[48], s_eb1[16];
    __shared__ float sBa[32], sBe[32];
    int tid = threadIdx.x;
    int bh = blockIdx.x;                  // b*480 + h
    int b = bh / HD, h = bh % HD;
    if (tid < 80) s_iw1[tid] = iw1[tid];
    if (tid >= 96 && tid < 112) s_ib1[tid - 96] = ib1[tid - 96];
    if (tid >= 128 && tid < 176) s_ew1[tid - 128] = ew1[tid - 128];
    if (tid >= 192 && tid < 208) s_eb1[tid - 192] = eb1[tid - 192];
    if (tid >= 208 && tid < 240) sBa[tid - 208] = ib2[tid - 208];
    if (tid >= 240 && tid < 256) sBe[tid - 240] = eb2[tid - 240];
    else if (tid < 16) sBe[16 + tid] = eb2[16 + tid];
    // weight A-fragments (zero-padded K beyond 16): built once
    int wv = tid >> 6, lane = tid & 63;
    int mrow = lane & 15, q = lane >> 4;
    bf16x8 wa[2], we[2];
    #pragma unroll
    for (int mt = 0; mt < 2; mt++) {
        int c = mt * 16 + mrow;
        bf16x8 va, ve;
        #pragma unroll
        for (int j = 0; j < 8; j++) {
            int k = q * 8 + j;
            va[j] = (k < 16) ? bf16s(iw2[k * 32 + c]) : (short)0;
            ve[j] = (k < 16) ? bf16s(ew2[k * 32 + c]) : (short)0;
        }
        wa[mt] = va; we[mt] = ve;
    }
    __syncthreads();
    float gx = (float)h * (1.0f / 479.0f);
    for (int w = tid; w < WD; w += 256) {
        size_t gid = (size_t)bh * WD + w;
        float gy = (float)w * (1.0f / 479.0f);
        float s0 = src[gid * 3 + 0];
        float s1 = src[gid * 3 + 1];
        float s2 = src[gid * 3 + 2];
        float xi = inp[gid];
        unsigned short ha[16], he[16];
        #pragma unroll
        for (int j = 0; j < 16; j++) {
            float va = s_ib1[j] + s0 * s_iw1[j] + s1 * s_iw1[16 + j] + s2 * s_iw1[32 + j]
                     + gx * s_iw1[48 + j] + gy * s_iw1[64 + j];
            ha[j] = (unsigned short)bf16s(gelu_f(va));
            float ve = s_eb1[j] + xi * s_ew1[j] + gx * s_ew1[16 + j] + gy * s_ew1[32 + j];
            he[j] = (unsigned short)bf16s(gelu_f(ve));
        }
        uint4* pa = reinterpret_cast<uint4*>(&hidA[w * 16]);
        uint4* pe = reinterpret_cast<uint4*>(&hidE[w * 16]);
        #pragma unroll
        for (int qq = 0; qq < 2; qq++) {
            pa[qq] = make_uint4(
                (unsigned)ha[qq*8+0] | ((unsigned)ha[qq*8+1] << 16),
                (unsigned)ha[qq*8+2] | ((unsigned)ha[qq*8+3] << 16),
                (unsigned)ha[qq*8+4] | ((unsigned)ha[qq*8+5] << 16),
                (unsigned)ha[qq*8+6] | ((unsigned)ha[qq*8+7] << 16));
            pe[qq] = make_uint4(
                (unsigned)he[qq*8+0] | ((unsigned)he[qq*8+1] << 16),
                (unsigned)he[qq*8+2] | ((unsigned)he[qq*8+3] << 16),
                (unsigned)he[qq*8+4] | ((unsigned)he[qq*8+5] << 16),
                (unsigned)he[qq*8+6] | ((unsigned)he[qq*8+7] << 16));
        }
    }
    __syncthreads();
    // Phase 2: 60 tasks (2 mt x 30 nt) over 4 waves.
    bf16x8 zero8 = {0,0,0,0,0,0,0,0};
    for (int t = wv; t < 60; t += 4) {
        int mt = t & 1, nt = t >> 1;
        int pix = nt * 16 + mrow;
        bf16x8 ba = (q < 2) ? *reinterpret_cast<const bf16x8*>(&hidA[pix * 16 + q * 8]) : zero8;
        bf16x8 be = (q < 2) ? *reinterpret_cast<const bf16x8*>(&hidE[pix * 16 + q * 8]) : zero8;
        f32x4 ca = {0.f, 0.f, 0.f, 0.f};
        f32x4 ce = {0.f, 0.f, 0.f, 0.f};
        ca = __builtin_amdgcn_mfma_f32_16x16x32_bf16(wa[mt], ba, ca, 0, 0, 0);
        ce = __builtin_amdgcn_mfma_f32_16x16x32_bf16(we[mt], be, ce, 0, 0, 0);
        int c0 = mt * 16 + q * 4;
        unsigned short usa[4], use_[4];
        float av[4], ev4[4];
        #pragma unroll
        for (int r = 0; r < 4; r++) {
            av[r] = ca[r] + sBa[c0 + r];
            ev4[r] = ce[r] + sBe[c0 + r];
            usa[r] = (unsigned short)bf16s(av[r]);
            use_[r] = (unsigned short)bf16s(ev4[r]);
        }
        size_t pixg = (size_t)bh * WD + pix;
        uint2 pka, pke;
        pka.x = (unsigned)usa[0] | ((unsigned)usa[1] << 16);
        pka.y = (unsigned)usa[2] | ((unsigned)usa[3] << 16);
        pke.x = (unsigned)use_[0] | ((unsigned)use_[1] << 16);
        pke.y = (unsigned)use_[2] | ((unsigned)use_[3] << 16);
        *reinterpret_cast<uint2*>(A2 + (pixg << 5) + c0) = pka;
        *reinterpret_cast<uint2*>(E2 + (pixg << 5) + c0) = pke;
        __hip_bfloat16* Gp = G3 + ((size_t)bh * 32 + c0) * 480 + pix;
        #pragma unroll
        for (int r = 0; r < 4; r++)
            Gp[r * 480] = __float2bfloat16(av[r] * ev4[r]);
    }
}

// All four swizzled twiddle fragment tables:
// Twig[0,45) | TinvF[45,105) | Tf2[105,255) | Ti1[255,435).
__global__ void k_tables(__hip_bfloat16* T) {
    int e = blockIdx.x * 256 + threadIdx.x;   // < 435*512
    if (e >= 435 * 512) return;
    int tile = e >> 9, r = e & 511;
    int lane = r >> 3, j = r & 7;
    float v = 0.0f;
    if (tile < 45) {                       // Twig: F1 row-DFT (K=480, N=48 pad)
        int kt = tile / 3, nt = tile % 3;
        int k = kt * 32 + ((lane >> 4) << 3) + j;
        int n = nt * 16 + (lane & 15);
        if (n < 40) {
            int ky = n >> 1;
            int idx = (k * ky) % NP;
            float ang = (float)idx * TWO_PI_OVER_NP;
            v = (n & 1) ? -sinf(ang) : cosf(ang);
        }
    } else if (tile < 105) {               // TinvF: I2 inverse-ky (K=64 pad, N=480), scale baked
        int t2 = tile - 45;
        int nt = t2 >> 1, kt = t2 & 1;
        int kk = kt * 32 + ((lane >> 4) << 3) + j;
        int w = nt * 16 + (lane & 15);
        if (kk < 40) {
            int ky = kk >> 1;
            int idx = (ky * w) % NP;
            float ang = (float)idx * TWO_PI_OVER_NP;
            float sc = (ky == 0 ? 1.0f : 2.0f) * (1.0f / 250000.0f);
            v = ((kk & 1) ? -sinf(ang) : cosf(ang)) * sc;
        }
    } else if (tile < 255) {               // Tf2: F2 h-DFT (K=960, N=80)
        int t2 = tile - 105;
        int kt = t2 / 5, nt = t2 % 5;
        int k = kt * 32 + ((lane >> 4) << 3) + j;
        int n = nt * 16 + (lane & 15);
        int hh = k >> 1, ri = k & 1;
        int kxi = n >> 1, part = n & 1;
        int kx = (kxi < 20) ? kxi : kxi + 460;
        int idx = (kx * hh) % NP;
        float ang = (float)idx * TWO_PI_OVER_NP;
        float c = cosf(ang), s = sinf(ang);
        v = (part == 0) ? (ri == 0 ? c : s) : (ri == 0 ? -s : c);
    } else {                               // Ti1: (hh,part)-major, K=(kxi,ri) pad 96
        int t2 = tile - 255;
        int nt = t2 / 3, kt = t2 % 3;
        int k = kt * 32 + ((lane >> 4) << 3) + j;
        int n = nt * 16 + (lane & 15);
        if (k < 80) {
            int kxi = k >> 1, ri = k & 1;
            int hh = n >> 1, part = n & 1;
            int kx = (kxi < 20) ? kxi : kxi + 460;
            int idx = (kx * hh) % NP;
            float ang = (float)idx * TWO_PI_OVER_NP;
            float c = cosf(ang), s = sinf(ang);
            v = (part == 0) ? (ri == 0 ? c : -s) : (ri == 0 ? s : c);
        }
    }
    T[e] = __float2bfloat16(v);
}

// F1 as pure single-stream MFMA GEMM over G3 row-blocks.
__global__ void __launch_bounds__(256) k_F1m(
    const __hip_bfloat16* G3, const __hip_bfloat16* Twig, __hip_bfloat16* Y1)
{
    int wv = threadIdx.x >> 6, lane = threadIdx.x & 63;
    int task = blockIdx.x * 4 + wv;          // < 5760
    int bh = task / 6, rem = task % 6;
    int mt = rem & 1, nt = rem >> 1;
    int b = bh / HD, h = bh % HD;
    int c = mt * 16 + (lane & 15);
    int koff = (lane >> 4) << 3;
    const __hip_bfloat16* grow = G3 + ((size_t)bh * 32 + c) * 480 + koff;
    f32x4 acc = {0.f, 0.f, 0.f, 0.f};
    #pragma unroll
    for (int kt = 0; kt < 15; kt++) {
        bf16x8 av = *reinterpret_cast<const bf16x8*>(grow + kt * 32);
        bf16x8 bv = *reinterpret_cast<const bf16x8*>(Twig + (((kt * 3 + nt) << 9) + lane * 8));
        acc = __builtin_amdgcn_mfma_f32_16x16x32_bf16(av, bv, acc, 0, 0, 0);
    }
    int n = nt * 16 + (lane & 15);
    if (n < 40) {
        int ky = n >> 1, part = n & 1;
        int crow = mt * 16 + ((lane >> 4) << 2);
        #pragma unroll
        for (int r = 0; r < 4; r++) {
            int cc = crow + r;
            Y1[((((size_t)(b * 32 + cc)) * WND + ky) * HD + h) * 2 + part] =
                __float2bfloat16(acc[r]);
        }
    }
}

// F2 as MFMA GEMM: M=1280 rows, K=960, N=80.
__global__ void __launch_bounds__(256) k_F2m(
    const __hip_bfloat16* Y1, const __hip_bfloat16* Tf2, float* Y2)
{
    int wv = threadIdx.x >> 6, lane = threadIdx.x & 63;
    int task = blockIdx.x * 4 + wv;          // < 400
    int mt = task / 5, nt = task % 5;
    int row = mt * 16 + (lane & 15);
    int koff = (lane >> 4) << 3;
    const __hip_bfloat16* arow = Y1 + (size_t)row * 960 + koff;
    f32x4 acc = {0.f, 0.f, 0.f, 0.f};
    #pragma unroll
    for (int kt = 0; kt < 30; kt++) {
        bf16x8 av = *reinterpret_cast<const bf16x8*>(arow + kt * 32);
        bf16x8 bv = *reinterpret_cast<const bf16x8*>(Tf2 + (((kt * 5 + nt) << 9) + lane * 8));
        acc = __builtin_amdgcn_mfma_f32_16x16x32_bf16(av, bv, acc, 0, 0, 0);
    }
    int n = nt * 16 + (lane & 15);
    int mb = mt * 16 + ((lane >> 4) << 2);
    #pragma unroll
    for (int r = 0; r < 4; r++)
        Y2[(size_t)(mb + r) * 80 + n] = acc[r];
}

// Channel mixing; writes Zb as bf16 rows [m][96] (cols 80..95 zero).
__global__ void __launch_bounds__(256) k_mix(
    const float* Y2, __hip_bfloat16* Zb,
    const float* fw1, const float* fw2, int l)
{
    int gid = blockIdx.x * 256 + threadIdx.x;  // < 122880
    int col = gid % 96;
    int row = gid / 96;
    if (col >= 80) { Zb[gid] = __float2bfloat16(0.0f); return; }
    int ky = row % 20;
    int oc = (row / 20) % 32;
    int b = row / 640;
    int z = col & 1;
    int kxi = col >> 1;
    const float* wp;
    int x;
    if (kxi < 20) { wp = fw1; x = kxi; } else { wp = fw2; x = kxi - 20; }
    size_t wbase = ((((size_t)(l * 32) * 32 + oc) * 20 + x) * 20 + ky) * 2 + z;
    const float* y2 = Y2 + ((size_t)b * 32 * 20 + ky) * 80 + kxi * 2 + z;
    float acc = 0.f;
    for (int i = 0; i < 32; i++) {
        float yv = y2[(size_t)i * 1600];
        float wv = wp[wbase + (size_t)i * 25600];
        acc += yv * wv;
    }
    Zb[gid] = __float2bfloat16(acc);
}

// I1 as transposed MFMA GEMM: U'[(hh,part)][(oc,ky)] = Ti1^T x Zb^T.
__global__ void __launch_bounds__(256) k_I1mt(
    const __hip_bfloat16* Zb, const __hip_bfloat16* Ti1, __hip_bfloat16* U2)
{
    int wv = threadIdx.x >> 6, lane = threadIdx.x & 63;
    int task = blockIdx.x * 4 + wv;          // < 4800
    int b = task / 2400, rem = task % 2400;
    int mt = rem / 40, nt = rem % 40;
    int koff = (lane >> 4) << 3;
    int nrow = nt * 16 + (lane & 15);        // n' = oc*20 + ky
    const __hip_bfloat16* brow = Zb + ((size_t)b * 640 + nrow) * 96 + koff;
    f32x4 acc = {0.f, 0.f, 0.f, 0.f};
    #pragma unroll
    for (int kt = 0; kt < 3; kt++) {
        bf16x8 av = *reinterpret_cast<const bf16x8*>(Ti1 + (((mt * 3 + kt) << 9) + lane * 8));
        bf16x8 bv = *reinterpret_cast<const bf16x8*>(brow + kt * 32);
        acc = __builtin_amdgcn_mfma_f32_16x16x32_bf16(av, bv, acc, 0, 0, 0);
    }
    int oc = nrow / 20, ky = nrow % 20;
    int mbase = mt * 16 + ((lane >> 4) << 2);
    #pragma unroll
    for (int r = 0; r < 4; r++) {
        int m = mbase + r;
        int hh = m >> 1, part = m & 1;
        U2[(((size_t)b * HD + hh) * 32 + oc) * 64 + ky * 2 + part] =
            __float2bfloat16(acc[r]);
    }
}

// I2: fine-split GEMM tasks (11520 waves). Outputs A2out (8B packed) and,
// for l<3, G3 = Anew*e in row-block layout (e from E2 via one 8B load).
__global__ void __launch_bounds__(256) k_I2s(
    const __hip_bfloat16* U2, const __hip_bfloat16* A2in,
    const __hip_bfloat16* E2, __hip_bfloat16* G3, __hip_bfloat16* A2out,
    const float* convw, const float* convb,
    const __hip_bfloat16* TinvF,
    int l, int do_gelu, int do_g)
{
    int tid = threadIdx.x;
    int wv = tid >> 6, lane = tid & 63;
    int task = blockIdx.x * 4 + wv;      // < 11520
    int bh = task / 12, rem = task % 12;
    int mt = rem & 1, ntg = rem >> 1;    // ntg in [0,6): tiles nt = ntg*5 .. +5
    int mrow = lane & 15, koff = (lane >> 4) << 3;
    int ocq = (lane >> 4) << 2;
    int oc = mt * 16 + mrow;
    const __hip_bfloat16* U2b = U2 + (size_t)bh * 32 * 64;
    bf16x8 uf0 = *reinterpret_cast<const bf16x8*>(U2b + oc * 64 + koff);
    bf16x8 uf1 = *reinterpret_cast<const bf16x8*>(U2b + oc * 64 + 32 + koff);
    bf16x8 wf;
    #pragma unroll
    for (int j = 0; j < 8; j++)
        wf[j] = bf16s(convw[(size_t)l * 1024 + oc * 32 + koff + j]);
    float bias[4];
    #pragma unroll
    for (int r = 0; r < 4; r++)
        bias[r] = convb[l * 32 + mt * 16 + ocq + r];
    const __hip_bfloat16* A2r = A2in + (size_t)bh * WD * 32;
    #pragma unroll
    for (int i = 0; i < 5; i++) {
        int nt = ntg * 5 + i;
        f32x4 acc = {0.f, 0.f, 0.f, 0.f};
        bf16x8 bv0 = *reinterpret_cast<const bf16x8*>(TinvF + (((nt * 2) << 9) + lane * 8));
        acc = __builtin_amdgcn_mfma_f32_16x16x32_bf16(uf0, bv0, acc, 0, 0, 0);
        bf16x8 bv1 = *reinterpret_cast<const bf16x8*>(TinvF + (((nt * 2 + 1) << 9) + lane * 8));
        acc = __builtin_amdgcn_mfma_f32_16x16x32_bf16(uf1, bv1, acc, 0, 0, 0);
        bf16x8 bv2 = *reinterpret_cast<const bf16x8*>(A2r + ((nt * 16 + mrow) << 5) + koff);
        acc = __builtin_amdgcn_mfma_f32_16x16x32_bf16(wf, bv2, acc, 0, 0, 0);
        int w = nt * 16 + mrow;
        int ocb = mt * 16 + ocq;
        unsigned short us[4];
        float vv[4];
        #pragma unroll
        for (int r = 0; r < 4; r++) {
            float v = acc[r] + bias[r];
            if (do_gelu) v = gelu_f(v);
            vv[r] = v;
            us[r] = (unsigned short)bf16s(v);
        }
        uint2 pk;
        pk.x = (unsigned)us[0] | ((unsigned)us[1] << 16);
        pk.y = (unsigned)us[2] | ((unsigned)us[3] << 16);
        *reinterpret_cast<uint2*>(A2out + (((size_t)bh * WD + w) << 5) + ocb) = pk;
        if (do_g) {
            uint2 epk = *reinterpret_cast<const uint2*>(E2 + (((size_t)bh * WD + w) << 5) + ocb);
            float e0 = bfbits2f((short)(epk.x & 0xffff));
            float e1 = bfbits2f((short)(epk.x >> 16));
            float e2 = bfbits2f((short)(epk.y & 0xffff));
            float e3 = bfbits2f((short)(epk.y >> 16));
            __hip_bfloat16* Gp = G3 + ((size_t)bh * 32 + ocb) * 480 + w;
            Gp[0]         = __float2bfloat16(vv[0] * e0);
            Gp[480]       = __float2bfloat16(vv[1] * e1);
            Gp[960]       = __float2bfloat16(vv[2] * e2);
            Gp[1440]      = __float2bfloat16(vv[3] * e3);
        }
    }
}

// Final: proj MLP + 3x3 mask conv + field*mask + pred. Reads pixel-major A2.
__global__ void __launch_bounds__(256) k_out(
    const __hip_bfloat16* A2fin, const float* inp, const float* src,
    const float* pw1, const float* pb1,
    const float* pw2, const float* pb2,
    const float* mw, const float* mb,
    float* out)
{
    __shared__ float sW1[CD * HALFD], sB1[HALFD], sW2[HALFD * 2], sB2[2], sM[9], sMB[1];
    int tid = threadIdx.x;
    for (int t = tid; t < CD * HALFD; t += 256) sW1[t] = pw1[t];
    if (tid < 16) sB1[tid] = pb1[tid];
    if (tid >= 32 && tid < 64) sW2[tid - 32] = pw2[tid - 32];
    if (tid >= 64 && tid < 66) sB2[tid - 64] = pb2[tid - 64];
    if (tid >= 96 && tid < 105) sM[tid - 96] = mw[tid - 96];
    if (tid == 128) sMB[0] = mb[0];
    __syncthreads();
    int gid = blockIdx.x * 256 + tid;  // < 460800
    int b = gid / PLANE;
    int r = gid % PLANE;
    int h = r / WD, w = r % WD;
    const bf16x8* ap = reinterpret_cast<const bf16x8*>(A2fin + (size_t)gid * 32);
    float av[32];
    #pragma unroll
    for (int q = 0; q < 4; q++) {
        bf16x8 v = ap[q];
        #pragma unroll
        for (int j = 0; j < 8; j++) av[q * 8 + j] = bfbits2f(v[j]);
    }
    float hid[16];
    #pragma unroll
    for (int j = 0; j < 16; j++) {
        float v = sB1[j];
        #pragma unroll
        for (int i = 0; i < 32; i++) v += av[i] * sW1[i * 16 + j];
        hid[j] = gelu_f(v);
    }
    float p0 = sB2[0], p1 = sB2[1];
    #pragma unroll
    for (int j = 0; j < 16; j++) { p0 += hid[j] * sW2[j * 2]; p1 += hid[j] * sW2[j * 2 + 1]; }
    float m = sMB[0];
    #pragma unroll
    for (int dh = 0; dh < 3; dh++) {
        int hh = h + dh - 1;
        #pragma unroll
        for (int dw = 0; dw < 3; dw++) {
            int ww = w + dw - 1;
            if (hh >= 0 && hh < HD && ww >= 0 && ww < WD)
                m += inp[(size_t)b * PLANE + (size_t)hh * WD + ww] * sM[dh * 3 + dw];
        }
    }
    float f0 = src[(size_t)gid * 3 + 1];
    float f1 = src[(size_t)gid * 3 + 2];
    out[(size_t)gid * 2 + 0] = f0 * m + p0;
    out[(size_t)gid * 2 + 1] = f1 * m + p1;
}

extern "C" void kernel_launch(void* const* d_in, const int* in_sizes, int n_in,
                              void* d_out, int out_size, void* d_ws, size_t ws_size,
                              hipStream_t stream) {
    const float* inp = (const float*)d_in[0];
    const float* src = (const float*)d_in[1];
    const float* iw1 = (const float*)d_in[2];
    const float* ib1 = (const float*)d_in[3];
    const float* iw2 = (const float*)d_in[4];
    const float* ib2 = (const float*)d_in[5];
    const float* ew1 = (const float*)d_in[6];
    const float* eb1 = (const float*)d_in[7];
    const float* ew2 = (const float*)d_in[8];
    const float* eb2 = (const float*)d_in[9];
    const float* fw1 = (const float*)d_in[10];
    const float* fw2 = (const float*)d_in[11];
    const float* cw  = (const float*)d_in[12];
    const float* cb  = (const float*)d_in[13];
    const float* pw1 = (const float*)d_in[14];
    const float* pb1 = (const float*)d_in[15];
    const float* pw2 = (const float*)d_in[16];
    const float* pb2 = (const float*)d_in[17];
    const float* mw  = (const float*)d_in[18];
    const float* mb  = (const float*)d_in[19];

    // Workspace (~125.5 MB):
    //   G3 row-block bf16 [bh][32][480] | E2 pixel-major | A2a, A2b (ping-pong)
    //   | Y1 bf16 | Y2 f32 | Zb bf16 | U2 bf16 [bh][32][64] | tables bf16
    const size_t NA = (size_t)BD * CD * PLANE;
    __hip_bfloat16* G3  = (__hip_bfloat16*)d_ws;
    __hip_bfloat16* E2  = G3 + NA;
    __hip_bfloat16* A2a = E2 + NA;
    __hip_bfloat16* A2b = A2a + NA;
    __hip_bfloat16* Y1  = A2b + NA;
    float* Y2 = (float*)(Y1 + (size_t)BD * CD * WND * HD * 2);
    __hip_bfloat16* Zb = (__hip_bfloat16*)(Y2 + 1280 * 80);
    __hip_bfloat16* U2 = Zb + 1280 * 96;
    __hip_bfloat16* Tbl   = U2 + (size_t)BD * HD * 32 * 64;
    __hip_bfloat16* Twig  = Tbl;
    __hip_bfloat16* TinvF = Twig + 45 * 512;
    __hip_bfloat16* Tf2   = TinvF + 60 * 512;
    __hip_bfloat16* Ti1   = Tf2 + 150 * 512;

    k_tables<<<870, 256, 0, stream>>>(Tbl);
    k_ae2<<<BD * HD, 256, 0, stream>>>(src, inp, iw1, ib1, iw2, ib2,
                                       ew1, eb1, ew2, eb2, A2a, E2, G3);

    __hip_bfloat16* ping[2] = {A2a, A2b};
    for (int l = 0; l < 4; l++) {
        k_F1m<<<1440, 256, 0, stream>>>(G3, Twig, Y1);
        k_F2m<<<100, 256, 0, stream>>>(Y1, Tf2, Y2);
        k_mix<<<480, 256, 0, stream>>>(Y2, Zb, fw1, fw2, l);
        k_I1mt<<<1200, 256, 0, stream>>>(Zb, Ti1, U2);
        k_I2s<<<2880, 256, 0, stream>>>(U2, ping[l & 1], E2, G3, ping[(l + 1) & 1],
                                        cw, cb, TinvF,
                                        l, (l < 3) ? 1 : 0, (l < 3) ? 1 : 0);
    }
    k_out<<<1800, 256, 0, stream>>>(ping[0], inp, src, pw1, pb1, pw2, pb2, mw, mb,
                                    (float*)d_out);
}